// Round 2
// baseline (2888.549 us; speedup 1.0000x reference)
//
#include <hip/hip_runtime.h>
#include <math.h>

#define EPS 1e-8f

__device__ __forceinline__ float sigmoidf_(float x) { return 1.0f / (1.0f + expf(-x)); }

// ---------------------------------------------------------------------------
// Weight concat: stack fwd/bwd W_ih into [768,K] + biases into [768]
// ---------------------------------------------------------------------------
__global__ __launch_bounds__(256) void prep_w_k(
    const float* __restrict__ rwf, const float* __restrict__ rwb,
    const float* __restrict__ rbf, const float* __restrict__ rbb,
    const float* __restrict__ awf, const float* __restrict__ awb,
    const float* __restrict__ abf, const float* __restrict__ abb,
    float* __restrict__ wcat_r, float* __restrict__ bcat_r,
    float* __restrict__ wcat_a, float* __restrict__ bcat_a)
{
    int idx = blockIdx.x * 256 + threadIdx.x;
    if (idx < 768 * 512) {
        int g = idx / 512, k = idx % 512;
        wcat_a[idx] = (g < 384) ? awf[g * 512 + k] : awb[(g - 384) * 512 + k];
    }
    if (idx < 768 * 300) {
        int g = idx / 300, k = idx % 300;
        wcat_r[idx] = (g < 384) ? rwf[g * 300 + k] : rwb[(g - 384) * 300 + k];
    }
    if (idx < 768) {
        bcat_r[idx] = (idx < 384) ? rbf[idx] : rbb[idx - 384];
        bcat_a[idx] = (idx < 384) ? abf[idx] : abb[idx - 384];
    }
}

// ---------------------------------------------------------------------------
// Generic tiled fp32 GEMM. TRANSB=true:  C[s] = A[s] * B[s/bdiv]^T (+bias)(+C)
//                          TRANSB=false: C[s] = A[s] * B[s/bdiv]   (+bias)(+C)
// A: [M x K] pitch lda.  B (NT): [N x K] pitch ldb.  B (NN): [K x N] pitch ldb.
// C: [M x N] pitch ldc. Tile 64x64xBK16, 256 threads, 4x4 per-thread.
// ---------------------------------------------------------------------------
template <bool TRANSB, bool ACC>
__global__ __launch_bounds__(256) void gemm_k(
    const float* __restrict__ A, const float* __restrict__ Bm,
    const float* __restrict__ bias, float* __restrict__ C,
    int M, int N, int K, int lda, int ldb, int ldc,
    long sA, long sB, int bdiv, long sC)
{
    const int jn = blockIdx.x * 64;
    const int im = blockIdx.y * 64;
    const int s  = blockIdx.z;
    const float* Ab = A + (size_t)s * sA;
    const float* Bb = Bm + (size_t)(s / bdiv) * sB;
    float* Cb = C + (size_t)s * sC;

    __shared__ __align__(16) float As[16][64];
    __shared__ __align__(16) float Bs[16][64];

    const int tid  = threadIdx.x;
    const int lrow = tid >> 2;        // 0..63
    const int lk   = (tid & 3) * 4;   // 0,4,8,12
    const int tm   = (tid >> 4) * 4;  // 0..60
    const int tn   = (tid & 15) * 4;  // 0..60

    float acc[4][4];
#pragma unroll
    for (int i = 0; i < 4; i++)
#pragma unroll
        for (int j = 0; j < 4; j++) acc[i][j] = 0.f;

    for (int k0 = 0; k0 < K; k0 += 16) {
        // ---- A tile (M x K row-major) -> As[k][m]
        {
            int row = im + lrow;
            int kk  = k0 + lk;
            float4 v = make_float4(0.f, 0.f, 0.f, 0.f);
            if (row < M) {
                if (kk + 4 <= K) v = *(const float4*)(Ab + (size_t)row * lda + kk);
                else {
                    if (kk + 0 < K) v.x = Ab[(size_t)row * lda + kk + 0];
                    if (kk + 1 < K) v.y = Ab[(size_t)row * lda + kk + 1];
                    if (kk + 2 < K) v.z = Ab[(size_t)row * lda + kk + 2];
                    if (kk + 3 < K) v.w = Ab[(size_t)row * lda + kk + 3];
                }
            }
            As[lk + 0][lrow] = v.x; As[lk + 1][lrow] = v.y;
            As[lk + 2][lrow] = v.z; As[lk + 3][lrow] = v.w;
        }
        // ---- B tile
        if constexpr (TRANSB) {       // B: N x K row-major -> Bs[k][n]
            int row = jn + lrow;
            int kk  = k0 + lk;
            float4 v = make_float4(0.f, 0.f, 0.f, 0.f);
            if (row < N) {
                if (kk + 4 <= K) v = *(const float4*)(Bb + (size_t)row * ldb + kk);
                else {
                    if (kk + 0 < K) v.x = Bb[(size_t)row * ldb + kk + 0];
                    if (kk + 1 < K) v.y = Bb[(size_t)row * ldb + kk + 1];
                    if (kk + 2 < K) v.z = Bb[(size_t)row * ldb + kk + 2];
                    if (kk + 3 < K) v.w = Bb[(size_t)row * ldb + kk + 3];
                }
            }
            Bs[lk + 0][lrow] = v.x; Bs[lk + 1][lrow] = v.y;
            Bs[lk + 2][lrow] = v.z; Bs[lk + 3][lrow] = v.w;
        } else {                      // B: K x N row-major -> Bs[k][n]
            int kk  = k0 + (tid >> 4);
            int col = jn + (tid & 15) * 4;
            float4 v = make_float4(0.f, 0.f, 0.f, 0.f);
            if (kk < K && col + 4 <= N) v = *(const float4*)(Bb + (size_t)kk * ldb + col);
            *(float4*)&Bs[tid >> 4][(tid & 15) * 4] = v;
        }
        __syncthreads();

#pragma unroll
        for (int kk = 0; kk < 16; kk++) {
            float4 a4 = *(const float4*)&As[kk][tm];
            float4 b4 = *(const float4*)&Bs[kk][tn];
            acc[0][0] += a4.x * b4.x; acc[0][1] += a4.x * b4.y; acc[0][2] += a4.x * b4.z; acc[0][3] += a4.x * b4.w;
            acc[1][0] += a4.y * b4.x; acc[1][1] += a4.y * b4.y; acc[1][2] += a4.y * b4.z; acc[1][3] += a4.y * b4.w;
            acc[2][0] += a4.z * b4.x; acc[2][1] += a4.z * b4.y; acc[2][2] += a4.z * b4.z; acc[2][3] += a4.z * b4.w;
            acc[3][0] += a4.w * b4.x; acc[3][1] += a4.w * b4.y; acc[3][2] += a4.w * b4.z; acc[3][3] += a4.w * b4.w;
        }
        __syncthreads();
    }

    float4 bv = make_float4(0.f, 0.f, 0.f, 0.f);
    if (bias) {
        bv.x = bias[jn + tn + 0]; bv.y = bias[jn + tn + 1];
        bv.z = bias[jn + tn + 2]; bv.w = bias[jn + tn + 3];
    }
#pragma unroll
    for (int r = 0; r < 4; r++) {
        int row = im + tm + r;
        if (row < M) {
            float* cp = Cb + (size_t)row * ldc + jn + tn;
            float4 o;
            o.x = acc[r][0] + bv.x; o.y = acc[r][1] + bv.y;
            o.z = acc[r][2] + bv.z; o.w = acc[r][3] + bv.w;
            if constexpr (ACC) {
                float4 old = *(const float4*)cp;
                o.x += old.x; o.y += old.y; o.z += old.z; o.w += old.w;
            }
            *(float4*)cp = o;
        }
    }
}

// ---------------------------------------------------------------------------
// GRU recurrence. One block per (seq, dir); 384 threads, thread g owns gate
// row g with W_hh[g][0:128] cached in VGPRs. h lives in LDS.
// gx layout: [(S*L) * 768], fwd gates at +0, bwd gates at +384.
// outs (optional): [S*L, 256]; hfin (optional): [S, 256].
// ---------------------------------------------------------------------------
__global__ __launch_bounds__(384) void gru_rec_k(
    const float* __restrict__ gx,
    const float* __restrict__ whh_f, const float* __restrict__ whh_b,
    const float* __restrict__ bhh_f, const float* __restrict__ bhh_b,
    float* __restrict__ outs, float* __restrict__ hfin, int L)
{
    const int dir = blockIdx.x & 1;
    const int s   = blockIdx.x >> 1;
    const int g   = threadIdx.x;
    const float* W  = dir ? whh_b : whh_f;
    const float* bh = dir ? bhh_b : bhh_f;

    float w[128];
#pragma unroll
    for (int i = 0; i < 32; i++) {
        float4 v = *(const float4*)(W + (size_t)g * 128 + i * 4);
        w[i * 4 + 0] = v.x; w[i * 4 + 1] = v.y; w[i * 4 + 2] = v.z; w[i * 4 + 3] = v.w;
    }
    const float bias = bh[g];

    __shared__ __align__(16) float hs[128];
    __shared__ float gxs[384];
    __shared__ float ghs[384];
    if (g < 128) hs[g] = 0.0f;
    __syncthreads();

    for (int t = 0; t < L; t++) {
        const int tt = dir ? (L - 1 - t) : t;
        const size_t rowoff = (size_t)s * L + tt;
        float xv = gx[rowoff * 768 + dir * 384 + g];
        float a0 = 0.f, a1 = 0.f, a2 = 0.f, a3 = 0.f;
#pragma unroll
        for (int k = 0; k < 128; k += 4) {
            float4 h4 = *(const float4*)(hs + k);
            a0 += w[k + 0] * h4.x;
            a1 += w[k + 1] * h4.y;
            a2 += w[k + 2] * h4.z;
            a3 += w[k + 3] * h4.w;
        }
        gxs[g] = xv;
        ghs[g] = (a0 + a1) + (a2 + a3) + bias;
        __syncthreads();
        if (g < 128) {
            float r = sigmoidf_(gxs[g] + ghs[g]);
            float z = sigmoidf_(gxs[g + 128] + ghs[g + 128]);
            float n = tanhf(gxs[g + 256] + r * ghs[g + 256]);
            float hnew = (1.0f - z) * n + z * hs[g];
            hs[g] = hnew;
            if (outs) outs[rowoff * 256 + dir * 128 + g] = hnew;
        }
        __syncthreads();
    }
    if (hfin && g < 128) hfin[(size_t)s * 256 + dir * 128 + g] = hs[g];
}

// ---------------------------------------------------------------------------
// Row inverse norms: rinv[row] = 1/max(||x[row,0:256]||, eps)
// ---------------------------------------------------------------------------
__global__ __launch_bounds__(256) void rowinv_k(const float* __restrict__ x,
                                                float* __restrict__ rinv)
{
    const int row = blockIdx.x;
    float v = x[(size_t)row * 256 + threadIdx.x];
    float ss = v * v;
#pragma unroll
    for (int o = 32; o > 0; o >>= 1) ss += __shfl_down(ss, o);
    __shared__ float ps[4];
    if ((threadIdx.x & 63) == 0) ps[threadIdx.x >> 6] = ss;
    __syncthreads();
    if (threadIdx.x == 0)
        rinv[row] = 1.0f / fmaxf(sqrtf(ps[0] + ps[1] + ps[2] + ps[3]), EPS);
}

// ---------------------------------------------------------------------------
// Fused cosine-scale + softmax over the 512 context positions of each att row.
// att chunk-local; sbase = global sequence index of chunk's first sequence.
// ---------------------------------------------------------------------------
__global__ __launch_bounds__(256) void att_softmax_k(
    float* __restrict__ att, const float* __restrict__ rinv_opt_l,
    const float* __restrict__ rinv_ctx, int sbase)
{
    const int row = blockIdx.x;          // chunk-local: s_local*50 + q
    const int b = (sbase + row / 50) / 10;
    float* p = att + (size_t)row * 512;
    const float* rc = rinv_ctx + b * 512;
    const float sA = rinv_opt_l[row];
    const int t = threadIdx.x;

    float v0 = p[t]       * (sA * rc[t]);
    float v1 = p[t + 256] * (sA * rc[t + 256]);

    __shared__ float red[4];
    float m = fmaxf(v0, v1);
#pragma unroll
    for (int o = 32; o > 0; o >>= 1) m = fmaxf(m, __shfl_down(m, o));
    if ((t & 63) == 0) red[t >> 6] = m;
    __syncthreads();
    m = fmaxf(fmaxf(red[0], red[1]), fmaxf(red[2], red[3]));
    float e0 = expf(v0 - m), e1 = expf(v1 - m);
    float ssum = e0 + e1;
#pragma unroll
    for (int o = 32; o > 0; o >>= 1) ssum += __shfl_down(ssum, o);
    __syncthreads();
    if ((t & 63) == 0) red[t >> 6] = ssum;
    __syncthreads();
    float inv = 1.0f / (red[0] + red[1] + red[2] + red[3]);
    p[t] = e0 * inv;
    p[t + 256] = e1 * inv;
}

// ---------------------------------------------------------------------------
// logits[s] = cosine(ctx_h[s/10], ao_h[s])
// ---------------------------------------------------------------------------
__global__ __launch_bounds__(256) void logits_k(const float* __restrict__ ch,
                                                const float* __restrict__ ah,
                                                float* __restrict__ logits)
{
    const int s = blockIdx.x;
    const int b = s / 10;
    const int t = threadIdx.x;
    float a = ch[b * 256 + t];
    float c = ah[(size_t)s * 256 + t];
    float num = a * c, na = a * a, nc = c * c;
#pragma unroll
    for (int o = 32; o > 0; o >>= 1) {
        num += __shfl_down(num, o);
        na  += __shfl_down(na,  o);
        nc  += __shfl_down(nc,  o);
    }
    __shared__ float pn[4], pa[4], pc[4];
    if ((t & 63) == 0) { pn[t >> 6] = num; pa[t >> 6] = na; pc[t >> 6] = nc; }
    __syncthreads();
    if (t == 0) {
        float sn = pn[0] + pn[1] + pn[2] + pn[3];
        float sa = pa[0] + pa[1] + pa[2] + pa[3];
        float sc = pc[0] + pc[1] + pc[2] + pc[3];
        logits[s] = sn / (fmaxf(sqrtf(sa), EPS) * fmaxf(sqrtf(sc), EPS));
    }
}

// ---------------------------------------------------------------------------
// Final softmax over the 10 options per batch row.
// ---------------------------------------------------------------------------
__global__ __launch_bounds__(64) void soft10_k(const float* __restrict__ logits,
                                               float* __restrict__ out)
{
    const int b = blockIdx.x;
    const int t = threadIdx.x;
    __shared__ float v[10];
    if (t < 10) v[t] = logits[b * 10 + t];
    __syncthreads();
    if (t < 10) {
        float m = v[0];
#pragma unroll
        for (int i = 1; i < 10; i++) m = fmaxf(m, v[i]);
        float ssum = 0.f;
#pragma unroll
        for (int i = 0; i < 10; i++) ssum += expf(v[i] - m);
        out[b * 10 + t] = expf(v[t] - m) / ssum;
    }
}

// ---------------------------------------------------------------------------
extern "C" void kernel_launch(void* const* d_in, const int* in_sizes, int n_in,
                              void* d_out, int out_size, void* d_ws, size_t ws_size,
                              hipStream_t stream)
{
    const float* context = (const float*)d_in[0];
    const float* options = (const float*)d_in[2];
    const float* rw_ih_f = (const float*)d_in[4];
    const float* rw_hh_f = (const float*)d_in[5];
    const float* rb_ih_f = (const float*)d_in[6];
    const float* rb_hh_f = (const float*)d_in[7];
    const float* rw_ih_b = (const float*)d_in[8];
    const float* rw_hh_b = (const float*)d_in[9];
    const float* rb_ih_b = (const float*)d_in[10];
    const float* rb_hh_b = (const float*)d_in[11];
    const float* aw_ih_f = (const float*)d_in[12];
    const float* aw_hh_f = (const float*)d_in[13];
    const float* ab_ih_f = (const float*)d_in[14];
    const float* ab_hh_f = (const float*)d_in[15];
    const float* aw_ih_b = (const float*)d_in[16];
    const float* aw_hh_b = (const float*)d_in[17];
    const float* ab_ih_b = (const float*)d_in[18];
    const float* ab_hh_b = (const float*)d_in[19];

    // --- adaptive chunking: pick least chunking whose layout fits ws_size ---
    // persistent floats: weights 625152 + ctx_outs 8388608 + ctx_h 16384 +
    //                    ao_h 163840 + logits 640 + rinv_ctx 32768 + rinv_opt 32000
    const size_t persist = 9259392;
    static const int cands[6][2] = {{1,1},{2,2},{2,4},{4,4},{8,8},{8,16}};
    int CC = 8, OC = 16;
    for (int i = 0; i < 6; i++) {
        size_t bc_ = 64 / cands[i][0], sc_ = 640 / cands[i][1];
        size_t p0 = bc_ * 512 * 768;
        if (sc_ * 38400 > p0) p0 = sc_ * 38400;
        size_t tot = persist + p0 + 2 * (sc_ * 12800);
        if (tot * 4 <= ws_size) { CC = cands[i][0]; OC = cands[i][1]; break; }
    }
    const int bc = 64 / CC;     // batches per ctx chunk
    const int sc = 640 / OC;    // sequences per option chunk (multiple of 10)
    size_t P0sz = (size_t)bc * 512 * 768;
    if ((size_t)sc * 38400 > P0sz) P0sz = (size_t)sc * 38400;

    float* ws       = (float*)d_ws;
    float* wcat_r   = ws;                       // [768,300]
    float* bcat_r   = wcat_r + 230400;          // [768]
    float* wcat_a   = bcat_r + 768;             // [768,512]
    float* bcat_a   = wcat_a + 393216;          // [768]
    float* ctx_outs = bcat_a + 768;             // [64*512,256]
    float* ctx_h    = ctx_outs + 8388608;       // [64,256]
    float* ao_h     = ctx_h + 16384;            // [640,256]
    float* logits   = ao_h + 163840;            // [640]
    float* rinv_ctx = logits + 640;             // [64*512]
    float* rinv_opt = rinv_ctx + 32768;         // [640*50]
    float* P0       = rinv_opt + 32000;         // gx / att pool
    float* P2       = P0 + P0sz;                // opt_outs chunk [sc*50,256]
    float* P3       = P2 + (size_t)sc * 12800;  // att_opt chunk  [sc*50,256]

    // 1. stack fwd/bwd input weights
    prep_w_k<<<1536, 256, 0, stream>>>(rw_ih_f, rw_ih_b, rb_ih_f, rb_ih_b,
                                       aw_ih_f, aw_ih_b, ab_ih_f, ab_ih_b,
                                       wcat_r, bcat_r, wcat_a, bcat_a);

    // 2. context: per chunk, gx GEMM then GRU recurrence
    for (int c = 0; c < CC; c++) {
        const int Mc = bc * 512;
        gemm_k<true, false><<<dim3(12, Mc / 64, 1), 256, 0, stream>>>(
            context + (size_t)c * Mc * 300, wcat_r, bcat_r, P0,
            Mc, 768, 300, 300, 300, 768, 0, 0, 1, 0);
        gru_rec_k<<<2 * bc, 384, 0, stream>>>(
            P0, rw_hh_f, rw_hh_b, rb_hh_f, rb_hh_b,
            ctx_outs + (size_t)c * Mc * 256, ctx_h + (size_t)c * bc * 256, 512);
    }

    // 3. ctx row inverse norms
    rowinv_k<<<32768, 256, 0, stream>>>(ctx_outs, rinv_ctx);

    // 4. options: per chunk pipeline
    for (int o = 0; o < OC; o++) {
        const int base = o * sc;          // global first sequence (multiple of 10)
        const int Mo = sc * 50;
        const float* ctxB = ctx_outs + (size_t)(base / 10) * 131072;

        // 4a. opt gx -> P0
        gemm_k<true, false><<<dim3(12, (Mo + 63) / 64, 1), 256, 0, stream>>>(
            options + (size_t)base * 50 * 300, wcat_r, bcat_r, P0,
            Mo, 768, 300, 300, 300, 768, 0, 0, 1, 0);
        // 4b. opt GRU -> P2 (opt_outs)
        gru_rec_k<<<2 * sc, 384, 0, stream>>>(
            P0, rw_hh_f, rw_hh_b, rb_hh_f, rb_hh_b, P2, nullptr, 50);
        // 4c. opt row inverse norms
        rowinv_k<<<Mo, 256, 0, stream>>>(P2, rinv_opt + (size_t)base * 50);
        // 4d. raw scores: att (aliases P0, gx dead) = opt_outs @ ctx_outs^T
        gemm_k<true, false><<<dim3(8, 1, sc), 256, 0, stream>>>(
            P2, ctxB, nullptr, P0,
            50, 512, 256, 256, 256, 512, 12800, 131072, 10, 25600);
        // 4e. fused cosine scaling + softmax
        att_softmax_k<<<Mo, 256, 0, stream>>>(P0, rinv_opt + (size_t)base * 50,
                                              rinv_ctx, base);
        // 4f. att_opt = att @ ctx_outs -> P3
        gemm_k<false, false><<<dim3(4, 1, sc), 256, 0, stream>>>(
            P0, ctxB, nullptr, P3,
            50, 256, 512, 512, 256, 256, 25600, 131072, 10, 12800);
        // 4g. attn gx (into P0, att dead) = att_opt@Wa[:,0:256]^T + b
        gemm_k<true, false><<<dim3(12, (Mo + 63) / 64, 1), 256, 0, stream>>>(
            P3, wcat_a, bcat_a, P0, Mo, 768, 256, 256, 512, 768, 0, 0, 1, 0);
        //     ... += opt_outs @ Wa[:,256:512]^T
        gemm_k<true, true><<<dim3(12, (Mo + 63) / 64, 1), 256, 0, stream>>>(
            P2, wcat_a + 256, nullptr, P0, Mo, 768, 256, 256, 512, 768, 0, 0, 1, 0);
        // 4h. attn GRU -> ao_h
        gru_rec_k<<<2 * sc, 384, 0, stream>>>(
            P0, aw_hh_f, aw_hh_b, ab_hh_f, ab_hh_b,
            nullptr, ao_h + (size_t)base * 256, 50);
    }

    // 5. cosine logits + final softmax over 10 options
    logits_k<<<640, 256, 0, stream>>>(ctx_h, ao_h, logits);
    soft10_k<<<64, 64, 0, stream>>>(logits, (float*)d_out);
}

// Round 3
// 2364.654 us; speedup vs baseline: 1.2216x; 1.2216x over previous
//
#include <hip/hip_runtime.h>
#include <math.h>

#define EPS 1e-8f

__device__ __forceinline__ float sigmoidf_(float x) { return 1.0f / (1.0f + expf(-x)); }

// ---------------------------------------------------------------------------
// Weight concat: stack fwd/bwd W_ih into [768,K] + biases into [768]
// ---------------------------------------------------------------------------
__global__ __launch_bounds__(256) void prep_w_k(
    const float* __restrict__ rwf, const float* __restrict__ rwb,
    const float* __restrict__ rbf, const float* __restrict__ rbb,
    const float* __restrict__ awf, const float* __restrict__ awb,
    const float* __restrict__ abf, const float* __restrict__ abb,
    float* __restrict__ wcat_r, float* __restrict__ bcat_r,
    float* __restrict__ wcat_a, float* __restrict__ bcat_a)
{
    int idx = blockIdx.x * 256 + threadIdx.x;
    if (idx < 768 * 512) {
        int g = idx / 512, k = idx % 512;
        wcat_a[idx] = (g < 384) ? awf[g * 512 + k] : awb[(g - 384) * 512 + k];
    }
    if (idx < 768 * 300) {
        int g = idx / 300, k = idx % 300;
        wcat_r[idx] = (g < 384) ? rwf[g * 300 + k] : rwb[(g - 384) * 300 + k];
    }
    if (idx < 768) {
        bcat_r[idx] = (idx < 384) ? rbf[idx] : rbb[idx - 384];
        bcat_a[idx] = (idx < 384) ? abf[idx] : abb[idx - 384];
    }
}

// ---------------------------------------------------------------------------
// Generic tiled fp32 GEMM. TRANSB=true:  C[s] = A[s] * B[s/bdiv]^T (+bias)(+C)
//                          TRANSB=false: C[s] = A[s] * B[s/bdiv]   (+bias)(+C)
// ---------------------------------------------------------------------------
template <bool TRANSB, bool ACC>
__global__ __launch_bounds__(256) void gemm_k(
    const float* __restrict__ A, const float* __restrict__ Bm,
    const float* __restrict__ bias, float* __restrict__ C,
    int M, int N, int K, int lda, int ldb, int ldc,
    long sA, long sB, int bdiv, long sC)
{
    const int jn = blockIdx.x * 64;
    const int im = blockIdx.y * 64;
    const int s  = blockIdx.z;
    const float* Ab = A + (size_t)s * sA;
    const float* Bb = Bm + (size_t)(s / bdiv) * sB;
    float* Cb = C + (size_t)s * sC;

    __shared__ __align__(16) float As[16][64];
    __shared__ __align__(16) float Bs[16][64];

    const int tid  = threadIdx.x;
    const int lrow = tid >> 2;        // 0..63
    const int lk   = (tid & 3) * 4;   // 0,4,8,12
    const int tm   = (tid >> 4) * 4;  // 0..60
    const int tn   = (tid & 15) * 4;  // 0..60

    float acc[4][4];
#pragma unroll
    for (int i = 0; i < 4; i++)
#pragma unroll
        for (int j = 0; j < 4; j++) acc[i][j] = 0.f;

    for (int k0 = 0; k0 < K; k0 += 16) {
        {
            int row = im + lrow;
            int kk  = k0 + lk;
            float4 v = make_float4(0.f, 0.f, 0.f, 0.f);
            if (row < M) {
                if (kk + 4 <= K) v = *(const float4*)(Ab + (size_t)row * lda + kk);
                else {
                    if (kk + 0 < K) v.x = Ab[(size_t)row * lda + kk + 0];
                    if (kk + 1 < K) v.y = Ab[(size_t)row * lda + kk + 1];
                    if (kk + 2 < K) v.z = Ab[(size_t)row * lda + kk + 2];
                    if (kk + 3 < K) v.w = Ab[(size_t)row * lda + kk + 3];
                }
            }
            As[lk + 0][lrow] = v.x; As[lk + 1][lrow] = v.y;
            As[lk + 2][lrow] = v.z; As[lk + 3][lrow] = v.w;
        }
        if constexpr (TRANSB) {
            int row = jn + lrow;
            int kk  = k0 + lk;
            float4 v = make_float4(0.f, 0.f, 0.f, 0.f);
            if (row < N) {
                if (kk + 4 <= K) v = *(const float4*)(Bb + (size_t)row * ldb + kk);
                else {
                    if (kk + 0 < K) v.x = Bb[(size_t)row * ldb + kk + 0];
                    if (kk + 1 < K) v.y = Bb[(size_t)row * ldb + kk + 1];
                    if (kk + 2 < K) v.z = Bb[(size_t)row * ldb + kk + 2];
                    if (kk + 3 < K) v.w = Bb[(size_t)row * ldb + kk + 3];
                }
            }
            Bs[lk + 0][lrow] = v.x; Bs[lk + 1][lrow] = v.y;
            Bs[lk + 2][lrow] = v.z; Bs[lk + 3][lrow] = v.w;
        } else {
            int kk  = k0 + (tid >> 4);
            int col = jn + (tid & 15) * 4;
            float4 v = make_float4(0.f, 0.f, 0.f, 0.f);
            if (kk < K && col + 4 <= N) v = *(const float4*)(Bb + (size_t)kk * ldb + col);
            *(float4*)&Bs[tid >> 4][(tid & 15) * 4] = v;
        }
        __syncthreads();

#pragma unroll
        for (int kk = 0; kk < 16; kk++) {
            float4 a4 = *(const float4*)&As[kk][tm];
            float4 b4 = *(const float4*)&Bs[kk][tn];
            acc[0][0] += a4.x * b4.x; acc[0][1] += a4.x * b4.y; acc[0][2] += a4.x * b4.z; acc[0][3] += a4.x * b4.w;
            acc[1][0] += a4.y * b4.x; acc[1][1] += a4.y * b4.y; acc[1][2] += a4.y * b4.z; acc[1][3] += a4.y * b4.w;
            acc[2][0] += a4.z * b4.x; acc[2][1] += a4.z * b4.y; acc[2][2] += a4.z * b4.z; acc[2][3] += a4.z * b4.w;
            acc[3][0] += a4.w * b4.x; acc[3][1] += a4.w * b4.y; acc[3][2] += a4.w * b4.z; acc[3][3] += a4.w * b4.w;
        }
        __syncthreads();
    }

    float4 bv = make_float4(0.f, 0.f, 0.f, 0.f);
    if (bias) {
        bv.x = bias[jn + tn + 0]; bv.y = bias[jn + tn + 1];
        bv.z = bias[jn + tn + 2]; bv.w = bias[jn + tn + 3];
    }
#pragma unroll
    for (int r = 0; r < 4; r++) {
        int row = im + tm + r;
        if (row < M) {
            float* cp = Cb + (size_t)row * ldc + jn + tn;
            float4 o;
            o.x = acc[r][0] + bv.x; o.y = acc[r][1] + bv.y;
            o.z = acc[r][2] + bv.z; o.w = acc[r][3] + bv.w;
            if constexpr (ACC) {
                float4 old = *(const float4*)cp;
                o.x += old.x; o.y += old.y; o.z += old.z; o.w += old.w;
            }
            *(float4*)cp = o;
        }
    }
}

// ---------------------------------------------------------------------------
// GRU recurrence, v2. One block per (seq, dir); 384 threads.
// Thread (rg, c): rows {2rg, 2rg+1}, k-slice [64c, 64c+64). 128 weight floats
// in VGPRs (__launch_bounds__(384,1) lifts the VGPR cap -> no spill; v1 showed
// VGPR_Count=104 < 128 => spilled weights, 3500 cyc/step).
// Wave-uniform h reads (16 ds_read_b128/wave/step), gx prefetched 1 step ahead.
// gx layout: [(S*L) * 768], fwd at +0, bwd at +384.
// ---------------------------------------------------------------------------
__global__ __launch_bounds__(384, 1) void gru_rec_k(
    const float* __restrict__ gx,
    const float* __restrict__ whh_f, const float* __restrict__ whh_b,
    const float* __restrict__ bhh_f, const float* __restrict__ bhh_b,
    float* __restrict__ outs, float* __restrict__ hfin, int L)
{
    const int dir = blockIdx.x & 1;
    const int s   = blockIdx.x >> 1;
    const int t   = threadIdx.x;      // 0..383
    const int c   = t / 192;          // k-half; wave-uniform (boundary at wave 3)
    const int rg  = t % 192;          // row-group
    const int r0  = 2 * rg, r1 = r0 + 1;
    const float* W  = dir ? whh_b : whh_f;
    const float* bh = dir ? bhh_b : bhh_f;

    float w0[64], w1[64];
#pragma unroll
    for (int i = 0; i < 16; i++) {
        float4 a = *(const float4*)(W + (size_t)r0 * 128 + 64 * c + 4 * i);
        float4 b = *(const float4*)(W + (size_t)r1 * 128 + 64 * c + 4 * i);
        w0[4*i+0] = a.x; w0[4*i+1] = a.y; w0[4*i+2] = a.z; w0[4*i+3] = a.w;
        w1[4*i+0] = b.x; w1[4*i+1] = b.y; w1[4*i+2] = b.z; w1[4*i+3] = b.w;
    }
    const float b0 = bh[r0];
    const float b1 = bh[r1];

    __shared__ __align__(16) float hs[128];
    __shared__ float gxs[384];
    __shared__ float sp[2][384];
    if (t < 128) hs[t] = 0.0f;
    __syncthreads();

    // prefetch gx for step 0
    {
        size_t ro0 = (size_t)s * L + (dir ? (L - 1) : 0);
        // nothing else
    }
    float xv = gx[((size_t)s * L + (dir ? (L - 1) : 0)) * 768 + dir * 384 + t];

    for (int it = 0; it < L; it++) {
        const int tt  = dir ? (L - 1 - it) : it;
        const int ttn = dir ? (tt > 0 ? tt - 1 : 0) : (tt < L - 1 ? tt + 1 : L - 1);
        const size_t ro  = (size_t)s * L + tt;
        const size_t ron = (size_t)s * L + ttn;
        const float xvn = gx[ron * 768 + dir * 384 + t];   // prefetch next step

        const float* hb = hs + 64 * c;
        float p0a = 0.f, p0b = 0.f, p1a = 0.f, p1b = 0.f;
#pragma unroll
        for (int j = 0; j < 64; j += 8) {
            float4 ha = *(const float4*)(hb + j);
            float4 hc = *(const float4*)(hb + j + 4);
            p0a += w0[j+0]*ha.x + w0[j+1]*ha.y + w0[j+2]*ha.z + w0[j+3]*ha.w;
            p0b += w0[j+4]*hc.x + w0[j+5]*hc.y + w0[j+6]*hc.z + w0[j+7]*hc.w;
            p1a += w1[j+0]*ha.x + w1[j+1]*ha.y + w1[j+2]*ha.z + w1[j+3]*ha.w;
            p1b += w1[j+4]*hc.x + w1[j+5]*hc.y + w1[j+6]*hc.z + w1[j+7]*hc.w;
        }
        gxs[t] = xv;
        if (c == 0) {
            sp[0][r0] = p0a + p0b + b0;
            sp[0][r1] = p1a + p1b + b1;
        } else {
            sp[1][r0] = p0a + p0b;
            sp[1][r1] = p1a + p1b;
        }
        __syncthreads();
        if (t < 128) {
            float ghr = sp[0][t]       + sp[1][t];
            float ghz = sp[0][t + 128] + sp[1][t + 128];
            float ghn = sp[0][t + 256] + sp[1][t + 256];
            float r = sigmoidf_(gxs[t] + ghr);
            float z = sigmoidf_(gxs[t + 128] + ghz);
            float n = tanhf(gxs[t + 256] + r * ghn);
            float hnew = (1.0f - z) * n + z * hs[t];
            hs[t] = hnew;
            if (outs) outs[ro * 256 + dir * 128 + t] = hnew;
        }
        __syncthreads();
        xv = xvn;
    }
    if (hfin && t < 128) hfin[(size_t)s * 256 + dir * 128 + t] = hs[t];
}

// ---------------------------------------------------------------------------
// Row inverse norms: rinv[row] = 1/max(||x[row,0:256]||, eps)
// ---------------------------------------------------------------------------
__global__ __launch_bounds__(256) void rowinv_k(const float* __restrict__ x,
                                                float* __restrict__ rinv)
{
    const int row = blockIdx.x;
    float v = x[(size_t)row * 256 + threadIdx.x];
    float ss = v * v;
#pragma unroll
    for (int o = 32; o > 0; o >>= 1) ss += __shfl_down(ss, o);
    __shared__ float ps[4];
    if ((threadIdx.x & 63) == 0) ps[threadIdx.x >> 6] = ss;
    __syncthreads();
    if (threadIdx.x == 0)
        rinv[row] = 1.0f / fmaxf(sqrtf(ps[0] + ps[1] + ps[2] + ps[3]), EPS);
}

// ---------------------------------------------------------------------------
// Fused cosine-scale + softmax over the 512 context positions of each att row.
// ---------------------------------------------------------------------------
__global__ __launch_bounds__(256) void att_softmax_k(
    float* __restrict__ att, const float* __restrict__ rinv_opt_l,
    const float* __restrict__ rinv_ctx, int sbase)
{
    const int row = blockIdx.x;          // chunk-local: s_local*50 + q
    const int b = (sbase + row / 50) / 10;
    float* p = att + (size_t)row * 512;
    const float* rc = rinv_ctx + b * 512;
    const float sA = rinv_opt_l[row];
    const int t = threadIdx.x;

    float v0 = p[t]       * (sA * rc[t]);
    float v1 = p[t + 256] * (sA * rc[t + 256]);

    __shared__ float red[4];
    float m = fmaxf(v0, v1);
#pragma unroll
    for (int o = 32; o > 0; o >>= 1) m = fmaxf(m, __shfl_down(m, o));
    if ((t & 63) == 0) red[t >> 6] = m;
    __syncthreads();
    m = fmaxf(fmaxf(red[0], red[1]), fmaxf(red[2], red[3]));
    float e0 = expf(v0 - m), e1 = expf(v1 - m);
    float ssum = e0 + e1;
#pragma unroll
    for (int o = 32; o > 0; o >>= 1) ssum += __shfl_down(ssum, o);
    __syncthreads();
    if ((t & 63) == 0) red[t >> 6] = ssum;
    __syncthreads();
    float inv = 1.0f / (red[0] + red[1] + red[2] + red[3]);
    p[t] = e0 * inv;
    p[t + 256] = e1 * inv;
}

// ---------------------------------------------------------------------------
// logits[s] = cosine(ctx_h[s/10], ao_h[s])
// ---------------------------------------------------------------------------
__global__ __launch_bounds__(256) void logits_k(const float* __restrict__ ch,
                                                const float* __restrict__ ah,
                                                float* __restrict__ logits)
{
    const int s = blockIdx.x;
    const int b = s / 10;
    const int t = threadIdx.x;
    float a = ch[b * 256 + t];
    float c = ah[(size_t)s * 256 + t];
    float num = a * c, na = a * a, nc = c * c;
#pragma unroll
    for (int o = 32; o > 0; o >>= 1) {
        num += __shfl_down(num, o);
        na  += __shfl_down(na,  o);
        nc  += __shfl_down(nc,  o);
    }
    __shared__ float pn[4], pa[4], pc[4];
    if ((t & 63) == 0) { pn[t >> 6] = num; pa[t >> 6] = na; pc[t >> 6] = nc; }
    __syncthreads();
    if (t == 0) {
        float sn = pn[0] + pn[1] + pn[2] + pn[3];
        float sa = pa[0] + pa[1] + pa[2] + pa[3];
        float sc = pc[0] + pc[1] + pc[2] + pc[3];
        logits[s] = sn / (fmaxf(sqrtf(sa), EPS) * fmaxf(sqrtf(sc), EPS));
    }
}

// ---------------------------------------------------------------------------
// Final softmax over the 10 options per batch row.
// ---------------------------------------------------------------------------
__global__ __launch_bounds__(64) void soft10_k(const float* __restrict__ logits,
                                               float* __restrict__ out)
{
    const int b = blockIdx.x;
    const int t = threadIdx.x;
    __shared__ float v[10];
    if (t < 10) v[t] = logits[b * 10 + t];
    __syncthreads();
    if (t < 10) {
        float m = v[0];
#pragma unroll
        for (int i = 1; i < 10; i++) m = fmaxf(m, v[i]);
        float ssum = 0.f;
#pragma unroll
        for (int i = 0; i < 10; i++) ssum += expf(v[i] - m);
        out[b * 10 + t] = expf(v[t] - m) / ssum;
    }
}

// ---------------------------------------------------------------------------
extern "C" void kernel_launch(void* const* d_in, const int* in_sizes, int n_in,
                              void* d_out, int out_size, void* d_ws, size_t ws_size,
                              hipStream_t stream)
{
    const float* context = (const float*)d_in[0];
    const float* options = (const float*)d_in[2];
    const float* rw_ih_f = (const float*)d_in[4];
    const float* rw_hh_f = (const float*)d_in[5];
    const float* rb_ih_f = (const float*)d_in[6];
    const float* rb_hh_f = (const float*)d_in[7];
    const float* rw_ih_b = (const float*)d_in[8];
    const float* rw_hh_b = (const float*)d_in[9];
    const float* rb_ih_b = (const float*)d_in[10];
    const float* rb_hh_b = (const float*)d_in[11];
    const float* aw_ih_f = (const float*)d_in[12];
    const float* aw_hh_f = (const float*)d_in[13];
    const float* ab_ih_f = (const float*)d_in[14];
    const float* ab_hh_f = (const float*)d_in[15];
    const float* aw_ih_b = (const float*)d_in[16];
    const float* aw_hh_b = (const float*)d_in[17];
    const float* ab_ih_b = (const float*)d_in[18];
    const float* ab_hh_b = (const float*)d_in[19];

    // --- adaptive chunking: pick least chunking whose layout fits ws_size ---
    const size_t persist = 9259392;
    static const int cands[6][2] = {{1,1},{2,2},{2,4},{4,4},{8,8},{8,16}};
    int CC = 8, OC = 16;
    for (int i = 0; i < 6; i++) {
        size_t bc_ = 64 / cands[i][0], sc_ = 640 / cands[i][1];
        size_t p0 = bc_ * 512 * 768;
        if (sc_ * 38400 > p0) p0 = sc_ * 38400;
        size_t tot = persist + p0 + 2 * (sc_ * 12800);
        if (tot * 4 <= ws_size) { CC = cands[i][0]; OC = cands[i][1]; break; }
    }
    const int bc = 64 / CC;     // batches per ctx chunk
    const int sc = 640 / OC;    // sequences per option chunk (multiple of 10)
    size_t P0sz = (size_t)bc * 512 * 768;
    if ((size_t)sc * 38400 > P0sz) P0sz = (size_t)sc * 38400;

    float* ws       = (float*)d_ws;
    float* wcat_r   = ws;                       // [768,300]
    float* bcat_r   = wcat_r + 230400;          // [768]
    float* wcat_a   = bcat_r + 768;             // [768,512]
    float* bcat_a   = wcat_a + 393216;          // [768]
    float* ctx_outs = bcat_a + 768;             // [64*512,256]
    float* ctx_h    = ctx_outs + 8388608;       // [64,256]
    float* ao_h     = ctx_h + 16384;            // [640,256]
    float* logits   = ao_h + 163840;            // [640]
    float* rinv_ctx = logits + 640;             // [64*512]
    float* rinv_opt = rinv_ctx + 32768;         // [640*50]
    float* P0       = rinv_opt + 32000;         // gx / att pool
    float* P2       = P0 + P0sz;                // opt_outs chunk [sc*50,256]
    float* P3       = P2 + (size_t)sc * 12800;  // att_opt chunk  [sc*50,256]

    // 1. stack fwd/bwd input weights
    prep_w_k<<<1536, 256, 0, stream>>>(rw_ih_f, rw_ih_b, rb_ih_f, rb_ih_b,
                                       aw_ih_f, aw_ih_b, ab_ih_f, ab_ih_b,
                                       wcat_r, bcat_r, wcat_a, bcat_a);

    // 2. context: per chunk, gx GEMM then GRU recurrence
    for (int c = 0; c < CC; c++) {
        const int Mc = bc * 512;
        gemm_k<true, false><<<dim3(12, Mc / 64, 1), 256, 0, stream>>>(
            context + (size_t)c * Mc * 300, wcat_r, bcat_r, P0,
            Mc, 768, 300, 300, 300, 768, 0, 0, 1, 0);
        gru_rec_k<<<2 * bc, 384, 0, stream>>>(
            P0, rw_hh_f, rw_hh_b, rb_hh_f, rb_hh_b,
            ctx_outs + (size_t)c * Mc * 256, ctx_h + (size_t)c * bc * 256, 512);
    }

    // 3. ctx row inverse norms
    rowinv_k<<<32768, 256, 0, stream>>>(ctx_outs, rinv_ctx);

    // 4. options: per chunk pipeline
    for (int o = 0; o < OC; o++) {
        const int base = o * sc;          // global first sequence (multiple of 10)
        const int Mo = sc * 50;
        const float* ctxB = ctx_outs + (size_t)(base / 10) * 131072;

        // 4a. opt gx -> P0
        gemm_k<true, false><<<dim3(12, (Mo + 63) / 64, 1), 256, 0, stream>>>(
            options + (size_t)base * 50 * 300, wcat_r, bcat_r, P0,
            Mo, 768, 300, 300, 300, 768, 0, 0, 1, 0);
        // 4b. opt GRU -> P2 (opt_outs)
        gru_rec_k<<<2 * sc, 384, 0, stream>>>(
            P0, rw_hh_f, rw_hh_b, rb_hh_f, rb_hh_b, P2, nullptr, 50);
        // 4c. opt row inverse norms
        rowinv_k<<<Mo, 256, 0, stream>>>(P2, rinv_opt + (size_t)base * 50);
        // 4d. raw scores: att (aliases P0, gx dead) = opt_outs @ ctx_outs^T
        gemm_k<true, false><<<dim3(8, 1, sc), 256, 0, stream>>>(
            P2, ctxB, nullptr, P0,
            50, 512, 256, 256, 256, 512, 12800, 131072, 10, 25600);
        // 4e. fused cosine scaling + softmax
        att_softmax_k<<<Mo, 256, 0, stream>>>(P0, rinv_opt + (size_t)base * 50,
                                              rinv_ctx, base);
        // 4f. att_opt = att @ ctx_outs -> P3
        gemm_k<false, false><<<dim3(4, 1, sc), 256, 0, stream>>>(
            P0, ctxB, nullptr, P3,
            50, 256, 512, 512, 256, 256, 25600, 131072, 10, 12800);
        // 4g. attn gx (into P0, att dead) = att_opt@Wa[:,0:256]^T + b
        gemm_k<true, false><<<dim3(12, (Mo + 63) / 64, 1), 256, 0, stream>>>(
            P3, wcat_a, bcat_a, P0, Mo, 768, 256, 256, 512, 768, 0, 0, 1, 0);
        //     ... += opt_outs @ Wa[:,256:512]^T
        gemm_k<true, true><<<dim3(12, (Mo + 63) / 64, 1), 256, 0, stream>>>(
            P2, wcat_a + 256, nullptr, P0, Mo, 768, 256, 256, 512, 768, 0, 0, 1, 0);
        // 4h. attn GRU -> ao_h
        gru_rec_k<<<2 * sc, 384, 0, stream>>>(
            P0, aw_hh_f, aw_hh_b, ab_hh_f, ab_hh_b,
            nullptr, ao_h + (size_t)base * 256, 50);
    }

    // 5. cosine logits + final softmax over 10 options
    logits_k<<<640, 256, 0, stream>>>(ctx_h, ao_h, logits);
    soft10_k<<<64, 64, 0, stream>>>(logits, (float*)d_out);
}

// Round 4
// 2317.255 us; speedup vs baseline: 1.2465x; 1.0205x over previous
//
#include <hip/hip_runtime.h>
#include <math.h>

#define EPS 1e-8f

__device__ __forceinline__ float fsig(float x)  { return 1.0f / (1.0f + __expf(-x)); }
__device__ __forceinline__ float ftanh(float x) { return 1.0f - 2.0f / (1.0f + __expf(2.0f * x)); }

// ---------------------------------------------------------------------------
// Weight concat: stack fwd/bwd W_ih into [768,K] + biases into [768]
// ---------------------------------------------------------------------------
__global__ __launch_bounds__(256) void prep_w_k(
    const float* __restrict__ rwf, const float* __restrict__ rwb,
    const float* __restrict__ rbf, const float* __restrict__ rbb,
    const float* __restrict__ awf, const float* __restrict__ awb,
    const float* __restrict__ abf, const float* __restrict__ abb,
    float* __restrict__ wcat_r, float* __restrict__ bcat_r,
    float* __restrict__ wcat_a, float* __restrict__ bcat_a)
{
    int idx = blockIdx.x * 256 + threadIdx.x;
    if (idx < 768 * 512) {
        int g = idx / 512, k = idx % 512;
        wcat_a[idx] = (g < 384) ? awf[g * 512 + k] : awb[(g - 384) * 512 + k];
    }
    if (idx < 768 * 300) {
        int g = idx / 300, k = idx % 300;
        wcat_r[idx] = (g < 384) ? rwf[g * 300 + k] : rwb[(g - 384) * 300 + k];
    }
    if (idx < 768) {
        bcat_r[idx] = (idx < 384) ? rbf[idx] : rbb[idx - 384];
        bcat_a[idx] = (idx < 384) ? abf[idx] : abb[idx - 384];
    }
}

// ---------------------------------------------------------------------------
// Generic tiled fp32 GEMM. TRANSB=true:  C[s] = A[s] * B[s/bdiv]^T (+bias)(+C)
//                          TRANSB=false: C[s] = A[s] * B[s/bdiv]   (+bias)(+C)
// ---------------------------------------------------------------------------
template <bool TRANSB, bool ACC>
__global__ __launch_bounds__(256) void gemm_k(
    const float* __restrict__ A, const float* __restrict__ Bm,
    const float* __restrict__ bias, float* __restrict__ C,
    int M, int N, int K, int lda, int ldb, int ldc,
    long sA, long sB, int bdiv, long sC)
{
    const int jn = blockIdx.x * 64;
    const int im = blockIdx.y * 64;
    const int s  = blockIdx.z;
    const float* Ab = A + (size_t)s * sA;
    const float* Bb = Bm + (size_t)(s / bdiv) * sB;
    float* Cb = C + (size_t)s * sC;

    __shared__ __align__(16) float As[16][64];
    __shared__ __align__(16) float Bs[16][64];

    const int tid  = threadIdx.x;
    const int lrow = tid >> 2;        // 0..63
    const int lk   = (tid & 3) * 4;   // 0,4,8,12
    const int tm   = (tid >> 4) * 4;  // 0..60
    const int tn   = (tid & 15) * 4;  // 0..60

    float acc[4][4];
#pragma unroll
    for (int i = 0; i < 4; i++)
#pragma unroll
        for (int j = 0; j < 4; j++) acc[i][j] = 0.f;

    for (int k0 = 0; k0 < K; k0 += 16) {
        {
            int row = im + lrow;
            int kk  = k0 + lk;
            float4 v = make_float4(0.f, 0.f, 0.f, 0.f);
            if (row < M) {
                if (kk + 4 <= K) v = *(const float4*)(Ab + (size_t)row * lda + kk);
                else {
                    if (kk + 0 < K) v.x = Ab[(size_t)row * lda + kk + 0];
                    if (kk + 1 < K) v.y = Ab[(size_t)row * lda + kk + 1];
                    if (kk + 2 < K) v.z = Ab[(size_t)row * lda + kk + 2];
                    if (kk + 3 < K) v.w = Ab[(size_t)row * lda + kk + 3];
                }
            }
            As[lk + 0][lrow] = v.x; As[lk + 1][lrow] = v.y;
            As[lk + 2][lrow] = v.z; As[lk + 3][lrow] = v.w;
        }
        if constexpr (TRANSB) {
            int row = jn + lrow;
            int kk  = k0 + lk;
            float4 v = make_float4(0.f, 0.f, 0.f, 0.f);
            if (row < N) {
                if (kk + 4 <= K) v = *(const float4*)(Bb + (size_t)row * ldb + kk);
                else {
                    if (kk + 0 < K) v.x = Bb[(size_t)row * ldb + kk + 0];
                    if (kk + 1 < K) v.y = Bb[(size_t)row * ldb + kk + 1];
                    if (kk + 2 < K) v.z = Bb[(size_t)row * ldb + kk + 2];
                    if (kk + 3 < K) v.w = Bb[(size_t)row * ldb + kk + 3];
                }
            }
            Bs[lk + 0][lrow] = v.x; Bs[lk + 1][lrow] = v.y;
            Bs[lk + 2][lrow] = v.z; Bs[lk + 3][lrow] = v.w;
        } else {
            int kk  = k0 + (tid >> 4);
            int col = jn + (tid & 15) * 4;
            float4 v = make_float4(0.f, 0.f, 0.f, 0.f);
            if (kk < K && col + 4 <= N) v = *(const float4*)(Bb + (size_t)kk * ldb + col);
            *(float4*)&Bs[tid >> 4][(tid & 15) * 4] = v;
        }
        __syncthreads();

#pragma unroll
        for (int kk = 0; kk < 16; kk++) {
            float4 a4 = *(const float4*)&As[kk][tm];
            float4 b4 = *(const float4*)&Bs[kk][tn];
            acc[0][0] += a4.x * b4.x; acc[0][1] += a4.x * b4.y; acc[0][2] += a4.x * b4.z; acc[0][3] += a4.x * b4.w;
            acc[1][0] += a4.y * b4.x; acc[1][1] += a4.y * b4.y; acc[1][2] += a4.y * b4.z; acc[1][3] += a4.y * b4.w;
            acc[2][0] += a4.z * b4.x; acc[2][1] += a4.z * b4.y; acc[2][2] += a4.z * b4.z; acc[2][3] += a4.z * b4.w;
            acc[3][0] += a4.w * b4.x; acc[3][1] += a4.w * b4.y; acc[3][2] += a4.w * b4.z; acc[3][3] += a4.w * b4.w;
        }
        __syncthreads();
    }

    float4 bv = make_float4(0.f, 0.f, 0.f, 0.f);
    if (bias) {
        bv.x = bias[jn + tn + 0]; bv.y = bias[jn + tn + 1];
        bv.z = bias[jn + tn + 2]; bv.w = bias[jn + tn + 3];
    }
#pragma unroll
    for (int r = 0; r < 4; r++) {
        int row = im + tm + r;
        if (row < M) {
            float* cp = Cb + (size_t)row * ldc + jn + tn;
            float4 o;
            o.x = acc[r][0] + bv.x; o.y = acc[r][1] + bv.y;
            o.z = acc[r][2] + bv.z; o.w = acc[r][3] + bv.w;
            if constexpr (ACC) {
                float4 old = *(const float4*)cp;
                o.x += old.x; o.y += old.y; o.z += old.z; o.w += old.w;
            }
            *(float4*)cp = o;
        }
    }
}

// ---------------------------------------------------------------------------
// GRU recurrence, v3. One block per (seq, dir); 512 threads = 128 owners x
// 4 k-slices (c = t>>7, wave-uniform). Thread (i,c) computes partials of gate
// rows {i, i+128, i+256} over k in [32c, 32c+32) with 96 weight floats in
// VGPRs (v2's 128-float array spilled: VGPR_Count=84). Owner (c==0) holds gx
// in registers (prefetched 1 step ahead), reduces partials from LDS, does the
// gate math, writes h. 2 barriers/step.
// gx layout: [(S*L) * 768], fwd at +0, bwd at +384.
// ---------------------------------------------------------------------------
__global__ __launch_bounds__(512, 1) void gru_rec_k(
    const float* __restrict__ gx,
    const float* __restrict__ whh_f, const float* __restrict__ whh_b,
    const float* __restrict__ bhh_f, const float* __restrict__ bhh_b,
    float* __restrict__ outs, float* __restrict__ hfin, int L)
{
    const int dir = blockIdx.x & 1;
    const int s   = blockIdx.x >> 1;
    const int t   = threadIdx.x;      // 0..511
    const int i   = t & 127;          // h index (owner when c==0)
    const int c   = t >> 7;           // k-slice, wave-uniform
    const float* W  = dir ? whh_b : whh_f;
    const float* bh = dir ? bhh_b : bhh_f;

    // weights: rows {i, i+128, i+256}, k-slice [32c, 32c+32)
    float4 w4[3][8];
#pragma unroll
    for (int j = 0; j < 3; j++) {
        const float* Wr = W + (size_t)(i + 128 * j) * 128 + 32 * c;
#pragma unroll
        for (int q = 0; q < 8; q++) w4[j][q] = *(const float4*)(Wr + 4 * q);
    }
    float b3[3] = {0.f, 0.f, 0.f};
    if (c == 0) {
#pragma unroll
        for (int j = 0; j < 3; j++) b3[j] = bh[i + 128 * j];
    }

    __shared__ __align__(16) float hs[128];
    __shared__ float sp[3][384];
    if (t < 128) hs[t] = 0.0f;
    __syncthreads();

    float xc0 = 0.f, xc1 = 0.f, xc2 = 0.f;
    if (c == 0) {
        const size_t ro0 = ((size_t)s * L + (dir ? (L - 1) : 0)) * 768 + dir * 384 + i;
        xc0 = gx[ro0]; xc1 = gx[ro0 + 128]; xc2 = gx[ro0 + 256];
    }

    for (int it = 0; it < L; it++) {
        const int tt  = dir ? (L - 1 - it) : it;
        const int itn = (it < L - 1) ? it + 1 : it;
        const int ttn = dir ? (L - 1 - itn) : itn;
        const size_t ro = (size_t)s * L + tt;

        float xn0 = 0.f, xn1 = 0.f, xn2 = 0.f;
        if (c == 0) {   // prefetch next step's gx (hidden behind this step)
            const size_t ron = ((size_t)s * L + ttn) * 768 + dir * 384 + i;
            xn0 = gx[ron]; xn1 = gx[ron + 128]; xn2 = gx[ron + 256];
        }

        const float* hb = hs + 32 * c;
        float4 h4[8];
#pragma unroll
        for (int q = 0; q < 8; q++) h4[q] = *(const float4*)(hb + 4 * q);

        float acc[3][2] = {{0.f, 0.f}, {0.f, 0.f}, {0.f, 0.f}};
#pragma unroll
        for (int q = 0; q < 8; q++) {
            const float4 h = h4[q];
#pragma unroll
            for (int j = 0; j < 3; j++) {
                acc[j][q & 1] += w4[j][q].x * h.x + w4[j][q].y * h.y +
                                 w4[j][q].z * h.z + w4[j][q].w * h.w;
            }
        }

        if (c != 0) {
#pragma unroll
            for (int j = 0; j < 3; j++)
                sp[c - 1][i + 128 * j] = acc[j][0] + acc[j][1];
        }
        __syncthreads();
        if (c == 0) {
            float gh0 = acc[0][0] + acc[0][1] + sp[0][i]       + sp[1][i]       + sp[2][i]       + b3[0];
            float gh1 = acc[1][0] + acc[1][1] + sp[0][i + 128] + sp[1][i + 128] + sp[2][i + 128] + b3[1];
            float gh2 = acc[2][0] + acc[2][1] + sp[0][i + 256] + sp[1][i + 256] + sp[2][i + 256] + b3[2];
            float r = fsig(xc0 + gh0);
            float z = fsig(xc1 + gh1);
            float n = ftanh(xc2 + r * gh2);
            float hnew = (1.0f - z) * n + z * hs[i];
            hs[i] = hnew;
            if (outs) outs[ro * 256 + dir * 128 + i] = hnew;
            xc0 = xn0; xc1 = xn1; xc2 = xn2;
        }
        __syncthreads();
    }
    if (hfin && c == 0) hfin[(size_t)s * 256 + dir * 128 + i] = hs[i];
}

// ---------------------------------------------------------------------------
// Row inverse norms: rinv[row] = 1/max(||x[row,0:256]||, eps)
// ---------------------------------------------------------------------------
__global__ __launch_bounds__(256) void rowinv_k(const float* __restrict__ x,
                                                float* __restrict__ rinv)
{
    const int row = blockIdx.x;
    float v = x[(size_t)row * 256 + threadIdx.x];
    float ss = v * v;
#pragma unroll
    for (int o = 32; o > 0; o >>= 1) ss += __shfl_down(ss, o);
    __shared__ float ps[4];
    if ((threadIdx.x & 63) == 0) ps[threadIdx.x >> 6] = ss;
    __syncthreads();
    if (threadIdx.x == 0)
        rinv[row] = 1.0f / fmaxf(sqrtf(ps[0] + ps[1] + ps[2] + ps[3]), EPS);
}

// ---------------------------------------------------------------------------
// Fused cosine-scale + softmax over the 512 context positions of each att row.
// ---------------------------------------------------------------------------
__global__ __launch_bounds__(256) void att_softmax_k(
    float* __restrict__ att, const float* __restrict__ rinv_opt_l,
    const float* __restrict__ rinv_ctx, int sbase)
{
    const int row = blockIdx.x;          // chunk-local: s_local*50 + q
    const int b = (sbase + row / 50) / 10;
    float* p = att + (size_t)row * 512;
    const float* rc = rinv_ctx + b * 512;
    const float sA = rinv_opt_l[row];
    const int t = threadIdx.x;

    float v0 = p[t]       * (sA * rc[t]);
    float v1 = p[t + 256] * (sA * rc[t + 256]);

    __shared__ float red[4];
    float m = fmaxf(v0, v1);
#pragma unroll
    for (int o = 32; o > 0; o >>= 1) m = fmaxf(m, __shfl_down(m, o));
    if ((t & 63) == 0) red[t >> 6] = m;
    __syncthreads();
    m = fmaxf(fmaxf(red[0], red[1]), fmaxf(red[2], red[3]));
    float e0 = __expf(v0 - m), e1 = __expf(v1 - m);
    float ssum = e0 + e1;
#pragma unroll
    for (int o = 32; o > 0; o >>= 1) ssum += __shfl_down(ssum, o);
    __syncthreads();
    if ((t & 63) == 0) red[t >> 6] = ssum;
    __syncthreads();
    float inv = 1.0f / (red[0] + red[1] + red[2] + red[3]);
    p[t] = e0 * inv;
    p[t + 256] = e1 * inv;
}

// ---------------------------------------------------------------------------
// logits[s] = cosine(ctx_h[s/10], ao_h[s])
// ---------------------------------------------------------------------------
__global__ __launch_bounds__(256) void logits_k(const float* __restrict__ ch,
                                                const float* __restrict__ ah,
                                                float* __restrict__ logits)
{
    const int s = blockIdx.x;
    const int b = s / 10;
    const int t = threadIdx.x;
    float a = ch[b * 256 + t];
    float c = ah[(size_t)s * 256 + t];
    float num = a * c, na = a * a, nc = c * c;
#pragma unroll
    for (int o = 32; o > 0; o >>= 1) {
        num += __shfl_down(num, o);
        na  += __shfl_down(na,  o);
        nc  += __shfl_down(nc,  o);
    }
    __shared__ float pn[4], pa[4], pc[4];
    if ((t & 63) == 0) { pn[t >> 6] = num; pa[t >> 6] = na; pc[t >> 6] = nc; }
    __syncthreads();
    if (t == 0) {
        float sn = pn[0] + pn[1] + pn[2] + pn[3];
        float sa = pa[0] + pa[1] + pa[2] + pa[3];
        float sc = pc[0] + pc[1] + pc[2] + pc[3];
        logits[s] = sn / (fmaxf(sqrtf(sa), EPS) * fmaxf(sqrtf(sc), EPS));
    }
}

// ---------------------------------------------------------------------------
// Final softmax over the 10 options per batch row.
// ---------------------------------------------------------------------------
__global__ __launch_bounds__(64) void soft10_k(const float* __restrict__ logits,
                                               float* __restrict__ out)
{
    const int b = blockIdx.x;
    const int t = threadIdx.x;
    __shared__ float v[10];
    if (t < 10) v[t] = logits[b * 10 + t];
    __syncthreads();
    if (t < 10) {
        float m = v[0];
#pragma unroll
        for (int i = 1; i < 10; i++) m = fmaxf(m, v[i]);
        float ssum = 0.f;
#pragma unroll
        for (int i = 0; i < 10; i++) ssum += __expf(v[i] - m);
        out[b * 10 + t] = __expf(v[t] - m) / ssum;
    }
}

// ---------------------------------------------------------------------------
extern "C" void kernel_launch(void* const* d_in, const int* in_sizes, int n_in,
                              void* d_out, int out_size, void* d_ws, size_t ws_size,
                              hipStream_t stream)
{
    const float* context = (const float*)d_in[0];
    const float* options = (const float*)d_in[2];
    const float* rw_ih_f = (const float*)d_in[4];
    const float* rw_hh_f = (const float*)d_in[5];
    const float* rb_ih_f = (const float*)d_in[6];
    const float* rb_hh_f = (const float*)d_in[7];
    const float* rw_ih_b = (const float*)d_in[8];
    const float* rw_hh_b = (const float*)d_in[9];
    const float* rb_ih_b = (const float*)d_in[10];
    const float* rb_hh_b = (const float*)d_in[11];
    const float* aw_ih_f = (const float*)d_in[12];
    const float* aw_hh_f = (const float*)d_in[13];
    const float* ab_ih_f = (const float*)d_in[14];
    const float* ab_hh_f = (const float*)d_in[15];
    const float* aw_ih_b = (const float*)d_in[16];
    const float* aw_hh_b = (const float*)d_in[17];
    const float* ab_ih_b = (const float*)d_in[18];
    const float* ab_hh_b = (const float*)d_in[19];

    // --- adaptive chunking; option buffers are carved inside the shared pool
    // pool = max(ctx-gx chunk, opt gx + opt_outs + att_opt chunk)
    const size_t persist = 9259392;
    static const int cands[6][2] = {{1,2},{2,2},{2,4},{4,4},{4,8},{8,16}};
    int CC = 8, OC = 16;
    size_t pool = 0;
    for (int idx = 0; idx < 6; idx++) {
        size_t bc_ = 64 / cands[idx][0], sc_ = 640 / cands[idx][1];
        size_t p = bc_ * 393216;
        if (sc_ * 64000 > p) p = sc_ * 64000;
        if ((persist + p) * 4 <= ws_size) { CC = cands[idx][0]; OC = cands[idx][1]; pool = p; break; }
    }
    if (pool == 0) {
        size_t bc_ = 8, sc_ = 40;
        pool = bc_ * 393216;
        if (sc_ * 64000 > pool) pool = sc_ * 64000;
    }
    const int bc = 64 / CC;     // batches per ctx chunk
    const int sc = 640 / OC;    // sequences per option chunk (multiple of 10)

    float* ws       = (float*)d_ws;
    float* wcat_r   = ws;                       // [768,300]
    float* bcat_r   = wcat_r + 230400;          // [768]
    float* wcat_a   = bcat_r + 768;             // [768,512]
    float* bcat_a   = wcat_a + 393216;          // [768]
    float* ctx_outs = bcat_a + 768;             // [64*512,256]
    float* ctx_h    = ctx_outs + 8388608;       // [64,256]
    float* ao_h     = ctx_h + 16384;            // [640,256]
    float* logits   = ao_h + 163840;            // [640]
    float* rinv_ctx = logits + 640;             // [64*512]
    float* rinv_opt = rinv_ctx + 32768;         // [640*50]
    float* P0       = rinv_opt + 32000;         // pool: ctx gx / opt gx / att
    float* P2       = P0 + (size_t)sc * 38400;  // opt_outs chunk [sc*50,256]
    float* P3       = P2 + (size_t)sc * 12800;  // att_opt chunk  [sc*50,256]

    // 1. stack fwd/bwd input weights
    prep_w_k<<<1536, 256, 0, stream>>>(rw_ih_f, rw_ih_b, rb_ih_f, rb_ih_b,
                                       aw_ih_f, aw_ih_b, ab_ih_f, ab_ih_b,
                                       wcat_r, bcat_r, wcat_a, bcat_a);

    // 2. context: per chunk, gx GEMM then GRU recurrence
    for (int c = 0; c < CC; c++) {
        const int Mc = bc * 512;
        gemm_k<true, false><<<dim3(12, Mc / 64, 1), 256, 0, stream>>>(
            context + (size_t)c * Mc * 300, wcat_r, bcat_r, P0,
            Mc, 768, 300, 300, 300, 768, 0, 0, 1, 0);
        gru_rec_k<<<2 * bc, 512, 0, stream>>>(
            P0, rw_hh_f, rw_hh_b, rb_hh_f, rb_hh_b,
            ctx_outs + (size_t)c * Mc * 256, ctx_h + (size_t)c * bc * 256, 512);
    }

    // 3. ctx row inverse norms
    rowinv_k<<<32768, 256, 0, stream>>>(ctx_outs, rinv_ctx);

    // 4. options: per chunk pipeline
    for (int o = 0; o < OC; o++) {
        const int base = o * sc;          // global first sequence (multiple of 10)
        const int Mo = sc * 50;
        const float* ctxB = ctx_outs + (size_t)(base / 10) * 131072;

        // 4a. opt gx -> P0
        gemm_k<true, false><<<dim3(12, (Mo + 63) / 64, 1), 256, 0, stream>>>(
            options + (size_t)base * 50 * 300, wcat_r, bcat_r, P0,
            Mo, 768, 300, 300, 300, 768, 0, 0, 1, 0);
        // 4b. opt GRU -> P2 (opt_outs)
        gru_rec_k<<<2 * sc, 512, 0, stream>>>(
            P0, rw_hh_f, rw_hh_b, rb_hh_f, rb_hh_b, P2, nullptr, 50);
        // 4c. opt row inverse norms
        rowinv_k<<<Mo, 256, 0, stream>>>(P2, rinv_opt + (size_t)base * 50);
        // 4d. raw scores: att (aliases P0, gx dead) = opt_outs @ ctx_outs^T
        gemm_k<true, false><<<dim3(8, 1, sc), 256, 0, stream>>>(
            P2, ctxB, nullptr, P0,
            50, 512, 256, 256, 256, 512, 12800, 131072, 10, 25600);
        // 4e. fused cosine scaling + softmax
        att_softmax_k<<<Mo, 256, 0, stream>>>(P0, rinv_opt + (size_t)base * 50,
                                              rinv_ctx, base);
        // 4f. att_opt = att @ ctx_outs -> P3
        gemm_k<false, false><<<dim3(4, 1, sc), 256, 0, stream>>>(
            P0, ctxB, nullptr, P3,
            50, 256, 512, 512, 256, 256, 25600, 131072, 10, 12800);
        // 4g. attn gx (into P0, att dead) = att_opt@Wa[:,0:256]^T + b
        gemm_k<true, false><<<dim3(12, (Mo + 63) / 64, 1), 256, 0, stream>>>(
            P3, wcat_a, bcat_a, P0, Mo, 768, 256, 256, 512, 768, 0, 0, 1, 0);
        //     ... += opt_outs @ Wa[:,256:512]^T
        gemm_k<true, true><<<dim3(12, (Mo + 63) / 64, 1), 256, 0, stream>>>(
            P2, wcat_a + 256, nullptr, P0, Mo, 768, 256, 256, 512, 768, 0, 0, 1, 0);
        // 4h. attn GRU -> ao_h
        gru_rec_k<<<2 * sc, 512, 0, stream>>>(
            P0, aw_hh_f, aw_hh_b, ab_hh_f, ab_hh_b,
            nullptr, ao_h + (size_t)base * 256, 50);
    }

    // 5. cosine logits + final softmax over 10 options
    logits_k<<<640, 256, 0, stream>>>(ctx_h, ao_h, logits);
    soft10_k<<<64, 64, 0, stream>>>(logits, (float*)d_out);
}

// Round 5
// 2104.068 us; speedup vs baseline: 1.3728x; 1.1013x over previous
//
#include <hip/hip_runtime.h>
#include <math.h>

#define EPS 1e-8f

typedef _Float16 h2_t __attribute__((ext_vector_type(2)));

__device__ __forceinline__ float fsig(float x)  { return 1.0f / (1.0f + __expf(-x)); }
__device__ __forceinline__ float ftanh(float x) { return 1.0f - 2.0f / (1.0f + __expf(2.0f * x)); }

// ---------------------------------------------------------------------------
// Weight concat: stack fwd/bwd W_ih into [768,K] + biases into [768]
// ---------------------------------------------------------------------------
__global__ __launch_bounds__(256) void prep_w_k(
    const float* __restrict__ rwf, const float* __restrict__ rwb,
    const float* __restrict__ rbf, const float* __restrict__ rbb,
    const float* __restrict__ awf, const float* __restrict__ awb,
    const float* __restrict__ abf, const float* __restrict__ abb,
    float* __restrict__ wcat_r, float* __restrict__ bcat_r,
    float* __restrict__ wcat_a, float* __restrict__ bcat_a)
{
    int idx = blockIdx.x * 256 + threadIdx.x;
    if (idx < 768 * 512) {
        int g = idx / 512, k = idx % 512;
        wcat_a[idx] = (g < 384) ? awf[g * 512 + k] : awb[(g - 384) * 512 + k];
    }
    if (idx < 768 * 300) {
        int g = idx / 300, k = idx % 300;
        wcat_r[idx] = (g < 384) ? rwf[g * 300 + k] : rwb[(g - 384) * 300 + k];
    }
    if (idx < 768) {
        bcat_r[idx] = (idx < 384) ? rbf[idx] : rbb[idx - 384];
        bcat_a[idx] = (idx < 384) ? abf[idx] : abb[idx - 384];
    }
}

// ---------------------------------------------------------------------------
// Generic tiled fp32 GEMM. TRANSB=true:  C[s] = A[s] * B[s/bdiv]^T (+bias)(+C)
//                          TRANSB=false: C[s] = A[s] * B[s/bdiv]   (+bias)(+C)
// ---------------------------------------------------------------------------
template <bool TRANSB, bool ACC>
__global__ __launch_bounds__(256) void gemm_k(
    const float* __restrict__ A, const float* __restrict__ Bm,
    const float* __restrict__ bias, float* __restrict__ C,
    int M, int N, int K, int lda, int ldb, int ldc,
    long sA, long sB, int bdiv, long sC)
{
    const int jn = blockIdx.x * 64;
    const int im = blockIdx.y * 64;
    const int s  = blockIdx.z;
    const float* Ab = A + (size_t)s * sA;
    const float* Bb = Bm + (size_t)(s / bdiv) * sB;
    float* Cb = C + (size_t)s * sC;

    __shared__ __align__(16) float As[16][64];
    __shared__ __align__(16) float Bs[16][64];

    const int tid  = threadIdx.x;
    const int lrow = tid >> 2;        // 0..63
    const int lk   = (tid & 3) * 4;   // 0,4,8,12
    const int tm   = (tid >> 4) * 4;  // 0..60
    const int tn   = (tid & 15) * 4;  // 0..60

    float acc[4][4];
#pragma unroll
    for (int i = 0; i < 4; i++)
#pragma unroll
        for (int j = 0; j < 4; j++) acc[i][j] = 0.f;

    for (int k0 = 0; k0 < K; k0 += 16) {
        {
            int row = im + lrow;
            int kk  = k0 + lk;
            float4 v = make_float4(0.f, 0.f, 0.f, 0.f);
            if (row < M) {
                if (kk + 4 <= K) v = *(const float4*)(Ab + (size_t)row * lda + kk);
                else {
                    if (kk + 0 < K) v.x = Ab[(size_t)row * lda + kk + 0];
                    if (kk + 1 < K) v.y = Ab[(size_t)row * lda + kk + 1];
                    if (kk + 2 < K) v.z = Ab[(size_t)row * lda + kk + 2];
                    if (kk + 3 < K) v.w = Ab[(size_t)row * lda + kk + 3];
                }
            }
            As[lk + 0][lrow] = v.x; As[lk + 1][lrow] = v.y;
            As[lk + 2][lrow] = v.z; As[lk + 3][lrow] = v.w;
        }
        if constexpr (TRANSB) {
            int row = jn + lrow;
            int kk  = k0 + lk;
            float4 v = make_float4(0.f, 0.f, 0.f, 0.f);
            if (row < N) {
                if (kk + 4 <= K) v = *(const float4*)(Bb + (size_t)row * ldb + kk);
                else {
                    if (kk + 0 < K) v.x = Bb[(size_t)row * ldb + kk + 0];
                    if (kk + 1 < K) v.y = Bb[(size_t)row * ldb + kk + 1];
                    if (kk + 2 < K) v.z = Bb[(size_t)row * ldb + kk + 2];
                    if (kk + 3 < K) v.w = Bb[(size_t)row * ldb + kk + 3];
                }
            }
            Bs[lk + 0][lrow] = v.x; Bs[lk + 1][lrow] = v.y;
            Bs[lk + 2][lrow] = v.z; Bs[lk + 3][lrow] = v.w;
        } else {
            int kk  = k0 + (tid >> 4);
            int col = jn + (tid & 15) * 4;
            float4 v = make_float4(0.f, 0.f, 0.f, 0.f);
            if (kk < K && col + 4 <= N) v = *(const float4*)(Bb + (size_t)kk * ldb + col);
            *(float4*)&Bs[tid >> 4][(tid & 15) * 4] = v;
        }
        __syncthreads();

#pragma unroll
        for (int kk = 0; kk < 16; kk++) {
            float4 a4 = *(const float4*)&As[kk][tm];
            float4 b4 = *(const float4*)&Bs[kk][tn];
            acc[0][0] += a4.x * b4.x; acc[0][1] += a4.x * b4.y; acc[0][2] += a4.x * b4.z; acc[0][3] += a4.x * b4.w;
            acc[1][0] += a4.y * b4.x; acc[1][1] += a4.y * b4.y; acc[1][2] += a4.y * b4.z; acc[1][3] += a4.y * b4.w;
            acc[2][0] += a4.z * b4.x; acc[2][1] += a4.z * b4.y; acc[2][2] += a4.z * b4.z; acc[2][3] += a4.z * b4.w;
            acc[3][0] += a4.w * b4.x; acc[3][1] += a4.w * b4.y; acc[3][2] += a4.w * b4.z; acc[3][3] += a4.w * b4.w;
        }
        __syncthreads();
    }

    float4 bv = make_float4(0.f, 0.f, 0.f, 0.f);
    if (bias) {
        bv.x = bias[jn + tn + 0]; bv.y = bias[jn + tn + 1];
        bv.z = bias[jn + tn + 2]; bv.w = bias[jn + tn + 3];
    }
#pragma unroll
    for (int r = 0; r < 4; r++) {
        int row = im + tm + r;
        if (row < M) {
            float* cp = Cb + (size_t)row * ldc + jn + tn;
            float4 o;
            o.x = acc[r][0] + bv.x; o.y = acc[r][1] + bv.y;
            o.z = acc[r][2] + bv.z; o.w = acc[r][3] + bv.w;
            if constexpr (ACC) {
                float4 old = *(const float4*)cp;
                o.x += old.x; o.y += old.y; o.z += old.z; o.w += old.w;
            }
            *(float4*)cp = o;
        }
    }
}

// ---------------------------------------------------------------------------
// GRU recurrence, v4. One block per (seq, dir); 512 threads = 128 owners x
// 4 k-slices. v3's 96-fp32 weight array spilled (VGPR=72): per-step 192 KB
// scratch refetch -> L2-BW-bound ~1780cyc/step. Fix: weights packed fp16x2
// (48 VGPRs -> inside the 72-84 envelope the allocator accepts) and
// v_dot2_f32_f16 (fp32 accumulate). h: fp32 master (hs) + packed fp16 shadow
// (h1) for the dot; per-wave h reads are wave-uniform broadcasts.
// gx layout: [(S*L) * 768], fwd at +0, bwd at +384.
// ---------------------------------------------------------------------------
__global__ __launch_bounds__(512, 2) void gru_rec_k(
    const float* __restrict__ gx,
    const float* __restrict__ whh_f, const float* __restrict__ whh_b,
    const float* __restrict__ bhh_f, const float* __restrict__ bhh_b,
    float* __restrict__ outs, float* __restrict__ hfin, int L)
{
    const int dir = blockIdx.x & 1;
    const int s   = blockIdx.x >> 1;
    const int t   = threadIdx.x;      // 0..511
    const int i   = t & 127;          // h index (owner when c==0)
    const int c   = t >> 7;           // k-slice [32c, 32c+32), wave-uniform
    const float* W  = dir ? whh_b : whh_f;
    const float* bh = dir ? bhh_b : bhh_f;

    // weights rows {i, i+128, i+256}, k-slice [32c,32c+32) -> 48 packed fp16x2
    h2_t w2[3][16];
#pragma unroll
    for (int j = 0; j < 3; j++) {
        const float* Wr = W + (size_t)(i + 128 * j) * 128 + 32 * c;
#pragma unroll
        for (int q = 0; q < 16; q++) {
            float2 f = *(const float2*)(Wr + 2 * q);
            h2_t p; p.x = (_Float16)f.x; p.y = (_Float16)f.y;
            w2[j][q] = p;
        }
    }
    float b3[3] = {0.f, 0.f, 0.f};
    if (c == 0) {
#pragma unroll
        for (int j = 0; j < 3; j++) b3[j] = bh[i + 128 * j];
    }

    __shared__ __align__(16) float hs[128];
    __shared__ __align__(4) _Float16 h1[128];
    __shared__ float sp[3][384];
    if (t < 128) { hs[t] = 0.0f; h1[t] = (_Float16)0.0f; }
    __syncthreads();

    float xc0 = 0.f, xc1 = 0.f, xc2 = 0.f;
    if (c == 0) {
        const size_t ro0 = ((size_t)s * L + (dir ? (L - 1) : 0)) * 768 + dir * 384 + i;
        xc0 = gx[ro0]; xc1 = gx[ro0 + 128]; xc2 = gx[ro0 + 256];
    }

    for (int it = 0; it < L; it++) {
        const int tt  = dir ? (L - 1 - it) : it;
        const int itn = (it < L - 1) ? it + 1 : it;
        const int ttn = dir ? (L - 1 - itn) : itn;
        const size_t ro = (size_t)s * L + tt;

        float xn0 = 0.f, xn1 = 0.f, xn2 = 0.f;
        if (c == 0) {   // prefetch next step's gx
            const size_t ron = ((size_t)s * L + ttn) * 768 + dir * 384 + i;
            xn0 = gx[ron]; xn1 = gx[ron + 128]; xn2 = gx[ron + 256];
        }

        const h2_t* hp = (const h2_t*)h1 + 16 * c;   // wave-uniform broadcast
        float a0 = 0.f, a1 = 0.f, a2 = 0.f;
#pragma unroll
        for (int q = 0; q < 16; q++) {
            h2_t hq = hp[q];
            a0 = __builtin_amdgcn_fdot2(w2[0][q], hq, a0, false);
            a1 = __builtin_amdgcn_fdot2(w2[1][q], hq, a1, false);
            a2 = __builtin_amdgcn_fdot2(w2[2][q], hq, a2, false);
        }

        if (c != 0) {
            sp[c - 1][i]       = a0;
            sp[c - 1][i + 128] = a1;
            sp[c - 1][i + 256] = a2;
        }
        __syncthreads();
        if (c == 0) {
            float gh0 = a0 + sp[0][i]       + sp[1][i]       + sp[2][i]       + b3[0];
            float gh1 = a1 + sp[0][i + 128] + sp[1][i + 128] + sp[2][i + 128] + b3[1];
            float gh2 = a2 + sp[0][i + 256] + sp[1][i + 256] + sp[2][i + 256] + b3[2];
            float r = fsig(xc0 + gh0);
            float z = fsig(xc1 + gh1);
            float n = ftanh(xc2 + r * gh2);
            float hnew = (1.0f - z) * n + z * hs[i];
            hs[i] = hnew;
            h1[i] = (_Float16)hnew;
            if (outs) outs[ro * 256 + dir * 128 + i] = hnew;
            xc0 = xn0; xc1 = xn1; xc2 = xn2;
        }
        __syncthreads();
    }
    if (hfin && c == 0) hfin[(size_t)s * 256 + dir * 128 + i] = hs[i];
}

// ---------------------------------------------------------------------------
// Row inverse norms: rinv[row] = 1/max(||x[row,0:256]||, eps)
// ---------------------------------------------------------------------------
__global__ __launch_bounds__(256) void rowinv_k(const float* __restrict__ x,
                                                float* __restrict__ rinv)
{
    const int row = blockIdx.x;
    float v = x[(size_t)row * 256 + threadIdx.x];
    float ss = v * v;
#pragma unroll
    for (int o = 32; o > 0; o >>= 1) ss += __shfl_down(ss, o);
    __shared__ float ps[4];
    if ((threadIdx.x & 63) == 0) ps[threadIdx.x >> 6] = ss;
    __syncthreads();
    if (threadIdx.x == 0)
        rinv[row] = 1.0f / fmaxf(sqrtf(ps[0] + ps[1] + ps[2] + ps[3]), EPS);
}

// ---------------------------------------------------------------------------
// Fused cosine-scale + softmax over the 512 context positions of each att row.
// ---------------------------------------------------------------------------
__global__ __launch_bounds__(256) void att_softmax_k(
    float* __restrict__ att, const float* __restrict__ rinv_opt_l,
    const float* __restrict__ rinv_ctx, int sbase)
{
    const int row = blockIdx.x;          // chunk-local: s_local*50 + q
    const int b = (sbase + row / 50) / 10;
    float* p = att + (size_t)row * 512;
    const float* rc = rinv_ctx + b * 512;
    const float sA = rinv_opt_l[row];
    const int t = threadIdx.x;

    float v0 = p[t]       * (sA * rc[t]);
    float v1 = p[t + 256] * (sA * rc[t + 256]);

    __shared__ float red[4];
    float m = fmaxf(v0, v1);
#pragma unroll
    for (int o = 32; o > 0; o >>= 1) m = fmaxf(m, __shfl_down(m, o));
    if ((t & 63) == 0) red[t >> 6] = m;
    __syncthreads();
    m = fmaxf(fmaxf(red[0], red[1]), fmaxf(red[2], red[3]));
    float e0 = __expf(v0 - m), e1 = __expf(v1 - m);
    float ssum = e0 + e1;
#pragma unroll
    for (int o = 32; o > 0; o >>= 1) ssum += __shfl_down(ssum, o);
    __syncthreads();
    if ((t & 63) == 0) red[t >> 6] = ssum;
    __syncthreads();
    float inv = 1.0f / (red[0] + red[1] + red[2] + red[3]);
    p[t] = e0 * inv;
    p[t + 256] = e1 * inv;
}

// ---------------------------------------------------------------------------
// logits[s] = cosine(ctx_h[s/10], ao_h[s])
// ---------------------------------------------------------------------------
__global__ __launch_bounds__(256) void logits_k(const float* __restrict__ ch,
                                                const float* __restrict__ ah,
                                                float* __restrict__ logits)
{
    const int s = blockIdx.x;
    const int b = s / 10;
    const int t = threadIdx.x;
    float a = ch[b * 256 + t];
    float c = ah[(size_t)s * 256 + t];
    float num = a * c, na = a * a, nc = c * c;
#pragma unroll
    for (int o = 32; o > 0; o >>= 1) {
        num += __shfl_down(num, o);
        na  += __shfl_down(na,  o);
        nc  += __shfl_down(nc,  o);
    }
    __shared__ float pn[4], pa[4], pc[4];
    if ((t & 63) == 0) { pn[t >> 6] = num; pa[t >> 6] = na; pc[t >> 6] = nc; }
    __syncthreads();
    if (t == 0) {
        float sn = pn[0] + pn[1] + pn[2] + pn[3];
        float sa = pa[0] + pa[1] + pa[2] + pa[3];
        float sc = pc[0] + pc[1] + pc[2] + pc[3];
        logits[s] = sn / (fmaxf(sqrtf(sa), EPS) * fmaxf(sqrtf(sc), EPS));
    }
}

// ---------------------------------------------------------------------------
// Final softmax over the 10 options per batch row.
// ---------------------------------------------------------------------------
__global__ __launch_bounds__(64) void soft10_k(const float* __restrict__ logits,
                                               float* __restrict__ out)
{
    const int b = blockIdx.x;
    const int t = threadIdx.x;
    __shared__ float v[10];
    if (t < 10) v[t] = logits[b * 10 + t];
    __syncthreads();
    if (t < 10) {
        float m = v[0];
#pragma unroll
        for (int i = 1; i < 10; i++) m = fmaxf(m, v[i]);
        float ssum = 0.f;
#pragma unroll
        for (int i = 0; i < 10; i++) ssum += __expf(v[i] - m);
        out[b * 10 + t] = __expf(v[t] - m) / ssum;
    }
}

// ---------------------------------------------------------------------------
extern "C" void kernel_launch(void* const* d_in, const int* in_sizes, int n_in,
                              void* d_out, int out_size, void* d_ws, size_t ws_size,
                              hipStream_t stream)
{
    const float* context = (const float*)d_in[0];
    const float* options = (const float*)d_in[2];
    const float* rw_ih_f = (const float*)d_in[4];
    const float* rw_hh_f = (const float*)d_in[5];
    const float* rb_ih_f = (const float*)d_in[6];
    const float* rb_hh_f = (const float*)d_in[7];
    const float* rw_ih_b = (const float*)d_in[8];
    const float* rw_hh_b = (const float*)d_in[9];
    const float* rb_ih_b = (const float*)d_in[10];
    const float* rb_hh_b = (const float*)d_in[11];
    const float* aw_ih_f = (const float*)d_in[12];
    const float* aw_hh_f = (const float*)d_in[13];
    const float* ab_ih_f = (const float*)d_in[14];
    const float* ab_hh_f = (const float*)d_in[15];
    const float* aw_ih_b = (const float*)d_in[16];
    const float* aw_hh_b = (const float*)d_in[17];
    const float* ab_ih_b = (const float*)d_in[18];
    const float* ab_hh_b = (const float*)d_in[19];

    // --- adaptive chunking; option buffers are carved inside the shared pool
    const size_t persist = 9259392;
    static const int cands[6][2] = {{1,2},{2,2},{2,4},{4,4},{4,8},{8,16}};
    int CC = 8, OC = 16;
    size_t pool = 0;
    for (int idx = 0; idx < 6; idx++) {
        size_t bc_ = 64 / cands[idx][0], sc_ = 640 / cands[idx][1];
        size_t p = bc_ * 393216;
        if (sc_ * 64000 > p) p = sc_ * 64000;
        if ((persist + p) * 4 <= ws_size) { CC = cands[idx][0]; OC = cands[idx][1]; pool = p; break; }
    }
    if (pool == 0) {
        size_t bc_ = 8, sc_ = 40;
        pool = bc_ * 393216;
        if (sc_ * 64000 > pool) pool = sc_ * 64000;
    }
    const int bc = 64 / CC;     // batches per ctx chunk
    const int sc = 640 / OC;    // sequences per option chunk (multiple of 10)

    float* ws       = (float*)d_ws;
    float* wcat_r   = ws;                       // [768,300]
    float* bcat_r   = wcat_r + 230400;          // [768]
    float* wcat_a   = bcat_r + 768;             // [768,512]
    float* bcat_a   = wcat_a + 393216;          // [768]
    float* ctx_outs = bcat_a + 768;             // [64*512,256]
    float* ctx_h    = ctx_outs + 8388608;       // [64,256]
    float* ao_h     = ctx_h + 16384;            // [640,256]
    float* logits   = ao_h + 163840;            // [640]
    float* rinv_ctx = logits + 640;             // [64*512]
    float* rinv_opt = rinv_ctx + 32768;         // [640*50]
    float* P0       = rinv_opt + 32000;         // pool: ctx gx / opt gx / att
    float* P2       = P0 + (size_t)sc * 38400;  // opt_outs chunk [sc*50,256]
    float* P3       = P2 + (size_t)sc * 12800;  // att_opt chunk  [sc*50,256]

    // 1. stack fwd/bwd input weights
    prep_w_k<<<1536, 256, 0, stream>>>(rw_ih_f, rw_ih_b, rb_ih_f, rb_ih_b,
                                       aw_ih_f, aw_ih_b, ab_ih_f, ab_ih_b,
                                       wcat_r, bcat_r, wcat_a, bcat_a);

    // 2. context: per chunk, gx GEMM then GRU recurrence
    for (int c = 0; c < CC; c++) {
        const int Mc = bc * 512;
        gemm_k<true, false><<<dim3(12, Mc / 64, 1), 256, 0, stream>>>(
            context + (size_t)c * Mc * 300, wcat_r, bcat_r, P0,
            Mc, 768, 300, 300, 300, 768, 0, 0, 1, 0);
        gru_rec_k<<<2 * bc, 512, 0, stream>>>(
            P0, rw_hh_f, rw_hh_b, rb_hh_f, rb_hh_b,
            ctx_outs + (size_t)c * Mc * 256, ctx_h + (size_t)c * bc * 256, 512);
    }

    // 3. ctx row inverse norms
    rowinv_k<<<32768, 256, 0, stream>>>(ctx_outs, rinv_ctx);

    // 4. options: per chunk pipeline
    for (int o = 0; o < OC; o++) {
        const int base = o * sc;          // global first sequence (multiple of 10)
        const int Mo = sc * 50;
        const float* ctxB = ctx_outs + (size_t)(base / 10) * 131072;

        // 4a. opt gx -> P0
        gemm_k<true, false><<<dim3(12, (Mo + 63) / 64, 1), 256, 0, stream>>>(
            options + (size_t)base * 50 * 300, wcat_r, bcat_r, P0,
            Mo, 768, 300, 300, 300, 768, 0, 0, 1, 0);
        // 4b. opt GRU -> P2 (opt_outs)
        gru_rec_k<<<2 * sc, 512, 0, stream>>>(
            P0, rw_hh_f, rw_hh_b, rb_hh_f, rb_hh_b, P2, nullptr, 50);
        // 4c. opt row inverse norms
        rowinv_k<<<Mo, 256, 0, stream>>>(P2, rinv_opt + (size_t)base * 50);
        // 4d. raw scores: att (aliases P0, gx dead) = opt_outs @ ctx_outs^T
        gemm_k<true, false><<<dim3(8, 1, sc), 256, 0, stream>>>(
            P2, ctxB, nullptr, P0,
            50, 512, 256, 256, 256, 512, 12800, 131072, 10, 25600);
        // 4e. fused cosine scaling + softmax
        att_softmax_k<<<Mo, 256, 0, stream>>>(P0, rinv_opt + (size_t)base * 50,
                                              rinv_ctx, base);
        // 4f. att_opt = att @ ctx_outs -> P3
        gemm_k<false, false><<<dim3(4, 1, sc), 256, 0, stream>>>(
            P0, ctxB, nullptr, P3,
            50, 256, 512, 512, 256, 256, 25600, 131072, 10, 12800);
        // 4g. attn gx (into P0, att dead) = att_opt@Wa[:,0:256]^T + b
        gemm_k<true, false><<<dim3(12, (Mo + 63) / 64, 1), 256, 0, stream>>>(
            P3, wcat_a, bcat_a, P0, Mo, 768, 256, 256, 512, 768, 0, 0, 1, 0);
        //     ... += opt_outs @ Wa[:,256:512]^T
        gemm_k<true, true><<<dim3(12, (Mo + 63) / 64, 1), 256, 0, stream>>>(
            P2, wcat_a + 256, nullptr, P0, Mo, 768, 256, 256, 512, 768, 0, 0, 1, 0);
        // 4h. attn GRU -> ao_h
        gru_rec_k<<<2 * sc, 512, 0, stream>>>(
            P0, aw_hh_f, aw_hh_b, ab_hh_f, ab_hh_b,
            nullptr, ao_h + (size_t)base * 256, 50);
    }

    // 5. cosine logits + final softmax over 10 options
    logits_k<<<640, 256, 0, stream>>>(ctx_h, ao_h, logits);
    soft10_k<<<64, 64, 0, stream>>>(logits, (float*)d_out);
}

// Round 6
// 1389.787 us; speedup vs baseline: 2.0784x; 1.5139x over previous
//
#include <hip/hip_runtime.h>
#include <math.h>

#define EPS 1e-8f

typedef _Float16 h2_t __attribute__((ext_vector_type(2)));
typedef _Float16 half8 __attribute__((ext_vector_type(8)));
typedef float f32x4 __attribute__((ext_vector_type(4)));

__device__ __forceinline__ float fsig(float x)  { return 1.0f / (1.0f + __expf(-x)); }
__device__ __forceinline__ float ftanh(float x) { return 1.0f - 2.0f / (1.0f + __expf(2.0f * x)); }

// ---------------------------------------------------------------------------
// Convert inputs + weights to fp16 (K padded 300->320 with zeros).
// ---------------------------------------------------------------------------
__global__ __launch_bounds__(256) void conv_k(
    const float* __restrict__ ctx, const float* __restrict__ opt,
    const float* __restrict__ rwf, const float* __restrict__ rwb,
    const float* __restrict__ awf, const float* __restrict__ awb,
    const float* __restrict__ rbf, const float* __restrict__ rbb,
    const float* __restrict__ abf, const float* __restrict__ abb,
    _Float16* __restrict__ ctxh, _Float16* __restrict__ opth,
    _Float16* __restrict__ wrh, _Float16* __restrict__ wah,
    float* __restrict__ br, float* __restrict__ ba)
{
    int idx = blockIdx.x * 256 + threadIdx.x;
    if (idx < 32768 * 320) {
        int r = idx / 320, k = idx % 320;
        ctxh[idx] = (k < 300) ? (_Float16)ctx[r * 300 + k] : (_Float16)0.f;
    }
    if (idx < 32000 * 320) {
        int r = idx / 320, k = idx % 320;
        opth[idx] = (k < 300) ? (_Float16)opt[r * 300 + k] : (_Float16)0.f;
    }
    if (idx < 768 * 320) {
        int g = idx / 320, k = idx % 320;
        float v = 0.f;
        if (k < 300) v = (g < 384) ? rwf[g * 300 + k] : rwb[(g - 384) * 300 + k];
        wrh[idx] = (_Float16)v;
    }
    if (idx < 768 * 512) {
        int g = idx / 512, k = idx % 512;
        wah[idx] = (_Float16)((g < 384) ? awf[g * 512 + k] : awb[(g - 384) * 512 + k]);
    }
    if (idx < 768) {
        br[idx] = (idx < 384) ? rbf[idx] : rbb[idx - 384];
        ba[idx] = (idx < 384) ? abf[idx] : abb[idx - 384];
    }
}

// ---------------------------------------------------------------------------
// fp16 MFMA GEMM, 64x64 tile, BK=32, 256 threads = 4 waves (2x2 of 32x32).
// C[z] = A[z] (opt: [A|A2] along K) * B[z/bdiv]^T + bias, fp32 accumulate,
// fp16 out. TRBS: B given as [K][N] row-major -> transpose-stage into LDS.
// Layouts (16x16x32 f16): A/B frag: m|n=lane&15, k=(lane>>4)*8+j;
// C/D: col=lane&15, row=(lane>>4)*4+reg.  [m89/m91-verified mappings]
// ---------------------------------------------------------------------------
template <bool TRBS, bool SPLITA, bool HASBIAS>
__global__ __launch_bounds__(256, 4) void hgemm_k(
    const _Float16* __restrict__ A, const _Float16* __restrict__ A2,
    const _Float16* __restrict__ B, const float* __restrict__ bias,
    _Float16* __restrict__ C, int M, int N, int K,
    int lda, int ldb, int ldc, long sA, long sB, int bdiv, long sC)
{
    const int jn = blockIdx.x * 64;
    const int im = blockIdx.y * 64;
    const int z  = blockIdx.z;
    const _Float16* Ab  = A + (size_t)z * sA;
    const _Float16* A2b = SPLITA ? (A2 + (size_t)z * sA) : nullptr;
    const _Float16* Bb  = B + (size_t)(z / bdiv) * sB;
    _Float16* Cb = C + (size_t)z * sC;

    __shared__ __align__(16) _Float16 As[64 * 32];
    __shared__ __align__(16) _Float16 Bs[64 * 32];

    const int tid  = threadIdx.x;
    const int arow = tid >> 2;          // 0..63
    const int akof = (tid & 3) * 8;     // 0,8,16,24
    const int lane = tid & 63;
    const int wv   = tid >> 6;          // 0..3
    const int wm   = (wv & 1) * 32;
    const int wn   = (wv >> 1) * 32;
    const int fm   = lane & 15;
    const int quad = lane >> 4;

    f32x4 acc[2][2];
#pragma unroll
    for (int a = 0; a < 2; a++)
#pragma unroll
        for (int b = 0; b < 2; b++) acc[a][b] = (f32x4)0.f;

    for (int k0 = 0; k0 < K; k0 += 32) {
        // ---- A tile: rows im..im+64, k k0..k0+32
        {
            half8 av = (half8)(_Float16)0.f;
            const int row = im + arow;
            if (row < M) {
                const int kg = k0 + akof;
                const _Float16* ap;
                if constexpr (SPLITA)
                    ap = (kg < 256) ? (Ab + (size_t)row * lda + kg)
                                    : (A2b + (size_t)row * lda + (kg - 256));
                else
                    ap = Ab + (size_t)row * lda + kg;
                av = *(const half8*)ap;
            }
            *(half8*)&As[arow * 32 + akof] = av;
        }
        // ---- B tile
        if constexpr (!TRBS) {          // B [N][K] rm (NT)
            half8 bv = *(const half8*)(Bb + (size_t)(jn + arow) * ldb + k0 + akof);
            *(half8*)&Bs[arow * 32 + akof] = bv;
        } else {                        // B [K][N] rm -> LDS [n][k]
            const int kk = tid >> 3, noff = (tid & 7) * 8;
            half8 bv = *(const half8*)(Bb + (size_t)(k0 + kk) * ldb + jn + noff);
#pragma unroll
            for (int e = 0; e < 8; e++) Bs[(noff + e) * 32 + kk] = bv[e];
        }
        __syncthreads();

        const _Float16* Asp = As + (wm + fm) * 32 + quad * 8;
        const _Float16* Bsp = Bs + (wn + fm) * 32 + quad * 8;
        half8 a0 = *(const half8*)Asp;
        half8 a1 = *(const half8*)(Asp + 16 * 32);
        half8 b0 = *(const half8*)Bsp;
        half8 b1 = *(const half8*)(Bsp + 16 * 32);
        acc[0][0] = __builtin_amdgcn_mfma_f32_16x16x32_f16(a0, b0, acc[0][0], 0, 0, 0);
        acc[0][1] = __builtin_amdgcn_mfma_f32_16x16x32_f16(a0, b1, acc[0][1], 0, 0, 0);
        acc[1][0] = __builtin_amdgcn_mfma_f32_16x16x32_f16(a1, b0, acc[1][0], 0, 0, 0);
        acc[1][1] = __builtin_amdgcn_mfma_f32_16x16x32_f16(a1, b1, acc[1][1], 0, 0, 0);
        __syncthreads();
    }

#pragma unroll
    for (int tm = 0; tm < 2; tm++) {
#pragma unroll
        for (int tn = 0; tn < 2; tn++) {
            const int col  = jn + wn + tn * 16 + fm;
            const int row0 = im + wm + tm * 16 + quad * 4;
            const float bv = HASBIAS ? bias[col] : 0.f;
#pragma unroll
            for (int r = 0; r < 4; r++) {
                const int row = row0 + r;
                if (row < M)
                    Cb[(size_t)row * ldc + col] = (_Float16)(acc[tm][tn][r] + bv);
            }
        }
    }
}

// ---------------------------------------------------------------------------
// GRU recurrence (v4 structure, fp16 gx in / fp16 outs). One block per
// (seq,dir); 512 threads = 128 owners x 4 k-slices; weights packed fp16x2 in
// VGPRs, v_dot2_f32_f16, fp32 h master + fp16 shadow.
// ---------------------------------------------------------------------------
__global__ __launch_bounds__(512, 2) void gru_rec_k(
    const _Float16* __restrict__ gx,
    const float* __restrict__ whh_f, const float* __restrict__ whh_b,
    const float* __restrict__ bhh_f, const float* __restrict__ bhh_b,
    _Float16* __restrict__ outs_h, float* __restrict__ hfin, int L)
{
    const int dir = blockIdx.x & 1;
    const int s   = blockIdx.x >> 1;
    const int t   = threadIdx.x;
    const int i   = t & 127;
    const int c   = t >> 7;
    const float* W  = dir ? whh_b : whh_f;
    const float* bh = dir ? bhh_b : bhh_f;

    h2_t w2[3][16];
#pragma unroll
    for (int j = 0; j < 3; j++) {
        const float* Wr = W + (size_t)(i + 128 * j) * 128 + 32 * c;
#pragma unroll
        for (int q = 0; q < 16; q++) {
            float2 f = *(const float2*)(Wr + 2 * q);
            h2_t p; p.x = (_Float16)f.x; p.y = (_Float16)f.y;
            w2[j][q] = p;
        }
    }
    float b3[3] = {0.f, 0.f, 0.f};
    if (c == 0) {
#pragma unroll
        for (int j = 0; j < 3; j++) b3[j] = bh[i + 128 * j];
    }

    __shared__ __align__(16) float hs[128];
    __shared__ __align__(4) _Float16 h1[128];
    __shared__ float sp[3][384];
    if (t < 128) { hs[t] = 0.0f; h1[t] = (_Float16)0.0f; }
    __syncthreads();

    float xc0 = 0.f, xc1 = 0.f, xc2 = 0.f;
    if (c == 0) {
        const size_t ro0 = ((size_t)s * L + (dir ? (L - 1) : 0)) * 768 + dir * 384 + i;
        xc0 = (float)gx[ro0]; xc1 = (float)gx[ro0 + 128]; xc2 = (float)gx[ro0 + 256];
    }

    for (int it = 0; it < L; it++) {
        const int tt  = dir ? (L - 1 - it) : it;
        const int itn = (it < L - 1) ? it + 1 : it;
        const int ttn = dir ? (L - 1 - itn) : itn;
        const size_t ro = (size_t)s * L + tt;

        float xn0 = 0.f, xn1 = 0.f, xn2 = 0.f;
        if (c == 0) {
            const size_t ron = ((size_t)s * L + ttn) * 768 + dir * 384 + i;
            xn0 = (float)gx[ron]; xn1 = (float)gx[ron + 128]; xn2 = (float)gx[ron + 256];
        }

        const h2_t* hp = (const h2_t*)h1 + 16 * c;
        float a0 = 0.f, a1 = 0.f, a2 = 0.f;
#pragma unroll
        for (int q = 0; q < 16; q++) {
            h2_t hq = hp[q];
            a0 = __builtin_amdgcn_fdot2(w2[0][q], hq, a0, false);
            a1 = __builtin_amdgcn_fdot2(w2[1][q], hq, a1, false);
            a2 = __builtin_amdgcn_fdot2(w2[2][q], hq, a2, false);
        }

        if (c != 0) {
            sp[c - 1][i]       = a0;
            sp[c - 1][i + 128] = a1;
            sp[c - 1][i + 256] = a2;
        }
        __syncthreads();
        if (c == 0) {
            float gh0 = a0 + sp[0][i]       + sp[1][i]       + sp[2][i]       + b3[0];
            float gh1 = a1 + sp[0][i + 128] + sp[1][i + 128] + sp[2][i + 128] + b3[1];
            float gh2 = a2 + sp[0][i + 256] + sp[1][i + 256] + sp[2][i + 256] + b3[2];
            float r = fsig(xc0 + gh0);
            float zz = fsig(xc1 + gh1);
            float n = ftanh(xc2 + r * gh2);
            float hnew = (1.0f - zz) * n + zz * hs[i];
            hs[i] = hnew;
            h1[i] = (_Float16)hnew;
            if (outs_h) outs_h[ro * 256 + dir * 128 + i] = (_Float16)hnew;
            xc0 = xn0; xc1 = xn1; xc2 = xn2;
        }
        __syncthreads();
    }
    if (hfin && c == 0) hfin[(size_t)s * 256 + dir * 128 + i] = hs[i];
}

// ---------------------------------------------------------------------------
// Row inverse norms over fp16 rows of 256.
// ---------------------------------------------------------------------------
__global__ __launch_bounds__(256) void rowinv_k(const _Float16* __restrict__ x,
                                                float* __restrict__ rinv)
{
    const int row = blockIdx.x;
    float v = (float)x[(size_t)row * 256 + threadIdx.x];
    float ss = v * v;
#pragma unroll
    for (int o = 32; o > 0; o >>= 1) ss += __shfl_down(ss, o);
    __shared__ float ps[4];
    if ((threadIdx.x & 63) == 0) ps[threadIdx.x >> 6] = ss;
    __syncthreads();
    if (threadIdx.x == 0)
        rinv[row] = 1.0f / fmaxf(sqrtf(ps[0] + ps[1] + ps[2] + ps[3]), EPS);
}

// ---------------------------------------------------------------------------
// Fused cosine-scale + softmax (fp16 in/out, 512 positions).
// ---------------------------------------------------------------------------
__global__ __launch_bounds__(256) void att_softmax_k(
    _Float16* __restrict__ att, const float* __restrict__ rinv_opt_l,
    const float* __restrict__ rinv_ctx, int sbase)
{
    const int row = blockIdx.x;
    const int b = (sbase + row / 50) / 10;
    _Float16* p = att + (size_t)row * 512;
    const float* rc = rinv_ctx + b * 512;
    const float sA = rinv_opt_l[row];
    const int t = threadIdx.x;

    float v0 = (float)p[t]       * (sA * rc[t]);
    float v1 = (float)p[t + 256] * (sA * rc[t + 256]);

    __shared__ float red[4];
    float m = fmaxf(v0, v1);
#pragma unroll
    for (int o = 32; o > 0; o >>= 1) m = fmaxf(m, __shfl_down(m, o));
    if ((t & 63) == 0) red[t >> 6] = m;
    __syncthreads();
    m = fmaxf(fmaxf(red[0], red[1]), fmaxf(red[2], red[3]));
    float e0 = __expf(v0 - m), e1 = __expf(v1 - m);
    float ssum = e0 + e1;
#pragma unroll
    for (int o = 32; o > 0; o >>= 1) ssum += __shfl_down(ssum, o);
    __syncthreads();
    if ((t & 63) == 0) red[t >> 6] = ssum;
    __syncthreads();
    float inv = 1.0f / (red[0] + red[1] + red[2] + red[3]);
    p[t]       = (_Float16)(e0 * inv);
    p[t + 256] = (_Float16)(e1 * inv);
}

// ---------------------------------------------------------------------------
// logits[s] = cosine(ctx_h[s/10], ao_h[s])
// ---------------------------------------------------------------------------
__global__ __launch_bounds__(256) void logits_k(const float* __restrict__ ch,
                                                const float* __restrict__ ah,
                                                float* __restrict__ logits)
{
    const int s = blockIdx.x;
    const int b = s / 10;
    const int t = threadIdx.x;
    float a = ch[b * 256 + t];
    float c = ah[(size_t)s * 256 + t];
    float num = a * c, na = a * a, nc = c * c;
#pragma unroll
    for (int o = 32; o > 0; o >>= 1) {
        num += __shfl_down(num, o);
        na  += __shfl_down(na,  o);
        nc  += __shfl_down(nc,  o);
    }
    __shared__ float pn[4], pa[4], pc[4];
    if ((t & 63) == 0) { pn[t >> 6] = num; pa[t >> 6] = na; pc[t >> 6] = nc; }
    __syncthreads();
    if (t == 0) {
        float sn = pn[0] + pn[1] + pn[2] + pn[3];
        float sa = pa[0] + pa[1] + pa[2] + pa[3];
        float sc = pc[0] + pc[1] + pc[2] + pc[3];
        logits[s] = sn / (fmaxf(sqrtf(sa), EPS) * fmaxf(sqrtf(sc), EPS));
    }
}

// ---------------------------------------------------------------------------
__global__ __launch_bounds__(64) void soft10_k(const float* __restrict__ logits,
                                               float* __restrict__ out)
{
    const int b = blockIdx.x;
    const int t = threadIdx.x;
    __shared__ float v[10];
    if (t < 10) v[t] = logits[b * 10 + t];
    __syncthreads();
    if (t < 10) {
        float m = v[0];
#pragma unroll
        for (int i = 1; i < 10; i++) m = fmaxf(m, v[i]);
        float ssum = 0.f;
#pragma unroll
        for (int i = 0; i < 10; i++) ssum += __expf(v[i] - m);
        out[b * 10 + t] = __expf(v[t] - m) / ssum;
    }
}

// ---------------------------------------------------------------------------
extern "C" void kernel_launch(void* const* d_in, const int* in_sizes, int n_in,
                              void* d_out, int out_size, void* d_ws, size_t ws_size,
                              hipStream_t stream)
{
    const float* context = (const float*)d_in[0];
    const float* options = (const float*)d_in[2];
    const float* rw_ih_f = (const float*)d_in[4];
    const float* rw_hh_f = (const float*)d_in[5];
    const float* rb_ih_f = (const float*)d_in[6];
    const float* rb_hh_f = (const float*)d_in[7];
    const float* rw_ih_b = (const float*)d_in[8];
    const float* rw_hh_b = (const float*)d_in[9];
    const float* rb_ih_b = (const float*)d_in[10];
    const float* rb_hh_b = (const float*)d_in[11];
    const float* aw_ih_f = (const float*)d_in[12];
    const float* aw_hh_f = (const float*)d_in[13];
    const float* ab_ih_f = (const float*)d_in[14];
    const float* ab_hh_f = (const float*)d_in[15];
    const float* aw_ih_b = (const float*)d_in[16];
    const float* aw_hh_b = (const float*)d_in[17];
    const float* ab_ih_b = (const float*)d_in[18];
    const float* ab_hh_b = (const float*)d_in[19];

    // --- chunk config: persist(fl)=15,123,840; pool=max(bc*196608, sc*19200);
    //     extras = sc*25600 (att fp16 + P2h + P3h)
    const size_t persist = 15123840;
    static const int cands[7][2] = {{1,4},{1,8},{1,16},{2,8},{2,16},{4,16},{8,16}};
    int CC = 8, OC = 16;
    for (int idx = 0; idx < 7; idx++) {
        size_t bc_ = 64 / cands[idx][0], sc_ = 640 / cands[idx][1];
        size_t p = bc_ * 196608;
        if (sc_ * 19200 > p) p = sc_ * 19200;
        if ((persist + p + sc_ * 25600) * 4 <= ws_size) {
            CC = cands[idx][0]; OC = cands[idx][1]; break;
        }
    }
    const int bc = 64 / CC;
    const int sc = 640 / OC;
    size_t poolsz = (size_t)bc * 196608;
    if ((size_t)sc * 19200 > poolsz) poolsz = (size_t)sc * 19200;

    float* ws = (float*)d_ws;
    size_t off = 0;
    _Float16* wrh   = (_Float16*)(ws + off); off += 122880;   // [768][320] h
    float*    br    = ws + off;              off += 768;
    _Float16* wah   = (_Float16*)(ws + off); off += 196608;   // [768][512] h
    float*    ba    = ws + off;              off += 768;
    _Float16* ctxh  = (_Float16*)(ws + off); off += 5242880;  // [32768][320] h
    _Float16* opth  = (_Float16*)(ws + off); off += 5120000;  // [32000][320] h
    _Float16* couts = (_Float16*)(ws + off); off += 4194304;  // [64*512][256] h
    float*    ctxhf = ws + off;              off += 16384;    // ctx h_fin
    float*    aohf  = ws + off;              off += 163840;   // ao h_fin
    float*    logits= ws + off;              off += 640;
    float*    rinvc = ws + off;              off += 32768;
    float*    rinvo = ws + off;              off += 32000;
    _Float16* POOL  = (_Float16*)(ws + off); off += poolsz;   // gx (ctx/opt/attn)
    _Float16* ATT   = (_Float16*)(ws + off); off += (size_t)sc * 12800;
    _Float16* P2H   = (_Float16*)(ws + off); off += (size_t)sc * 6400;
    _Float16* P3H   = (_Float16*)(ws + off); off += (size_t)sc * 6400;

    // 1. fp16 conversion of inputs + weights (padded K=320)
    conv_k<<<40960, 256, 0, stream>>>(context, options,
                                      rw_ih_f, rw_ih_b, aw_ih_f, aw_ih_b,
                                      rb_ih_f, rb_ih_b, ab_ih_f, ab_ih_b,
                                      ctxh, opth, wrh, wah, br, ba);

    // 2. context: gx GEMM (MFMA) + GRU per chunk
    for (int c = 0; c < CC; c++) {
        const int Mc = bc * 512;
        hgemm_k<false, false, true><<<dim3(12, Mc / 64, 1), 256, 0, stream>>>(
            ctxh + (size_t)c * Mc * 320, nullptr, wrh, br, POOL,
            Mc, 768, 320, 320, 320, 768, 0, 0, 1, 0);
        gru_rec_k<<<2 * bc, 512, 0, stream>>>(
            POOL, rw_hh_f, rw_hh_b, rb_hh_f, rb_hh_b,
            couts + (size_t)c * Mc * 256, ctxhf + (size_t)c * bc * 256, 512);
    }

    // 3. ctx row inverse norms
    rowinv_k<<<32768, 256, 0, stream>>>(couts, rinvc);

    // 4. options: per chunk pipeline
    for (int o = 0; o < OC; o++) {
        const int base = o * sc;
        const int Mo = sc * 50;
        const _Float16* ctxB = couts + (size_t)(base / 10) * 131072;

        // 4a. opt gx (MFMA) -> POOL
        hgemm_k<false, false, true><<<dim3(12, (Mo + 63) / 64, 1), 256, 0, stream>>>(
            opth + (size_t)base * 50 * 320, nullptr, wrh, br, POOL,
            Mo, 768, 320, 320, 320, 768, 0, 0, 1, 0);
        // 4b. opt GRU -> P2H
        gru_rec_k<<<2 * sc, 512, 0, stream>>>(
            POOL, rw_hh_f, rw_hh_b, rb_hh_f, rb_hh_b, P2H, nullptr, 50);
        // 4c. opt row inverse norms
        rowinv_k<<<Mo, 256, 0, stream>>>(P2H, rinvo + (size_t)base * 50);
        // 4d. raw scores (MFMA, NT, batched): ATT = P2H @ ctxB^T
        hgemm_k<false, false, false><<<dim3(8, 1, sc), 256, 0, stream>>>(
            P2H, nullptr, ctxB, nullptr, ATT,
            50, 512, 256, 256, 256, 512, 12800, 131072, 10, 25600);
        // 4e. fused cosine scaling + softmax (fp16 in-place)
        att_softmax_k<<<Mo, 256, 0, stream>>>(ATT, rinvo + (size_t)base * 50,
                                              rinvc, base);
        // 4f. att_opt (MFMA, NN via transpose-stage): P3H = ATT @ ctxB
        hgemm_k<true, false, false><<<dim3(4, 1, sc), 256, 0, stream>>>(
            ATT, nullptr, ctxB, nullptr, P3H,
            50, 256, 512, 512, 256, 256, 25600, 131072, 10, 12800);
        // 4g. attn gx (MFMA, split-A K=512): POOL = [P3H|P2H] @ wah^T + ba
        hgemm_k<false, true, true><<<dim3(12, (Mo + 63) / 64, 1), 256, 0, stream>>>(
            P3H, P2H, wah, ba, POOL,
            Mo, 768, 512, 256, 512, 768, 0, 0, 1, 0);
        // 4h. attn GRU -> ao_h
        gru_rec_k<<<2 * sc, 512, 0, stream>>>(
            POOL, aw_hh_f, aw_hh_b, ab_hh_f, ab_hh_b,
            nullptr, aohf + (size_t)base * 256, 50);
    }

    // 5. cosine logits + final softmax
    logits_k<<<640, 256, 0, stream>>>(ctxhf, aohf, logits);
    soft10_k<<<64, 64, 0, stream>>>(logits, (float*)d_out);
}